// Round 3
// baseline (1649.706 us; speedup 1.0000x reference)
//
#include <hip/hip_runtime.h>
#include <hip/hip_bf16.h>

// CQAttention: B=16, Lc=1024, Lq=512, d=512.  f32 I/O (confirmed by rounds 0-2
// evidence), f32 accumulate, bf16 intermediates (MFMA-ready error-budget test).
// Round 3: f32-input correctness round. ws = 72.1 MiB aliased (confirmed fits).

#define NB 16
#define LC 1024
#define LQ 512
#define DM 512
#define D4 2048
#define NEGINF (-1e30f)

typedef __hip_bfloat16 bf16;

__device__ __forceinline__ float b2f(bf16 x) { return __bfloat162float(x); }
__device__ __forceinline__ bf16  f2b(float x) { return __float2bfloat16(x); }
__device__ __forceinline__ int emap(int b4, int q) { return (q < 4) ? (b4 + q) : (60 + b4 + q); }

// ---------------- flags ----------------
__global__ void k_zeroflags(int* f) { *f = 0; }

__global__ void k_scan_f32(const unsigned int* __restrict__ p, long n, int* __restrict__ flags) {
  long i = (long)blockIdx.x * 256 + threadIdx.x;
  int bad = 0;
  for (; i < n; i += (long)gridDim.x * 256) {
    unsigned int u = p[i];
    if ((u & 0x7F800000u) == 0x7F800000u) bad = 1;   // f32 Inf or NaN
  }
  if (bad) atomicOr(flags, 1);
}

__global__ void k_finalize(const int* __restrict__ flags, int hostflags, float* __restrict__ out) {
  int f = *flags | hostflags;
  if (f) out[0] = 1000.f * (float)f;
}

// ---------------- K1: cw1[b,i] = C.w1, qw2[b,j] = Q.w2 ----------------
__global__ void k_rowdots(const float* __restrict__ C, const float* __restrict__ Q,
                          const float* __restrict__ w,
                          float* __restrict__ cw1, float* __restrict__ qw2) {
  const int wid = threadIdx.x >> 6, lane = threadIdx.x & 63;
  const int row = blockIdx.x * 4 + wid;
  const bool isC = row < NB * LC;
  const float* src = isC ? (C + (size_t)row * DM) : (Q + (size_t)(row - NB * LC) * DM);
  const float* wv  = isC ? w : (w + DM);
  float v = 0.f;
#pragma unroll
  for (int tt = 0; tt < 8; ++tt) {
    int k = lane + 64 * tt;
    v += src[k] * wv[k];
  }
#pragma unroll
  for (int off = 32; off; off >>= 1) v += __shfl_down(v, off, 64);
  if (lane == 0) {
    if (isC) cw1[row] = v;
    else     qw2[row - NB * LC] = v;
  }
}

// ---------------- shared 128x128x8 f32 GEMM inner step ----------------
__device__ __forceinline__ void mm8x8(float (*As)[132], float (*Bs)[132],
                                      float acc[8][8], int tx4, int ty4) {
#pragma unroll
  for (int kk = 0; kk < 8; ++kk) {
    float a[8], b[8];
#pragma unroll
    for (int u = 0; u < 4; ++u) { a[u] = As[kk][ty4 + u]; a[4 + u] = As[kk][64 + ty4 + u]; }
#pragma unroll
    for (int v = 0; v < 4; ++v) { b[v] = Bs[kk][tx4 + v]; b[4 + v] = Bs[kk][64 + tx4 + v]; }
#pragma unroll
    for (int u = 0; u < 8; ++u)
#pragma unroll
      for (int v = 0; v < 8; ++v) acc[u][v] = fmaf(a[u], b[v], acc[u][v]);
  }
}

// ---------------- G1: S[b,i,j] = cw1 + qw2 + (C.w3) @ Q^T ----------------
__global__ void k_gemm_S(const float* __restrict__ C, const float* __restrict__ Q,
                         const float* __restrict__ w,
                         const float* __restrict__ cw1, const float* __restrict__ qw2,
                         float* __restrict__ S) {
  __shared__ float As[8][132], Bs[8][132];
  const int b = blockIdx.z;
  const int i0 = blockIdx.y * 128, j0 = blockIdx.x * 128;
  const float* Cb = C + (size_t)b * LC * DM;
  const float* Qb = Q + (size_t)b * LQ * DM;
  const float* w3 = w + 2 * DM;
  const int t = threadIdx.x;
  const int tx4 = (t & 15) * 4, ty4 = (t >> 4) * 4;
  const int lr = t >> 1, lc4 = (t & 1) * 4;
  float acc[8][8];
#pragma unroll
  for (int u = 0; u < 8; ++u)
#pragma unroll
    for (int v = 0; v < 8; ++v) acc[u][v] = 0.f;

  for (int k0 = 0; k0 < DM; k0 += 8) {
#pragma unroll
    for (int u = 0; u < 4; ++u) {
      int k = k0 + lc4 + u;
      As[lc4 + u][lr] = Cb[(size_t)(i0 + lr) * DM + k] * w3[k];
      Bs[lc4 + u][lr] = Qb[(size_t)(j0 + lr) * DM + k];
    }
    __syncthreads();
    mm8x8(As, Bs, acc, tx4, ty4);
    __syncthreads();
  }
#pragma unroll
  for (int u = 0; u < 8; ++u) {
    int i = i0 + emap(ty4, u);
    float ra = cw1[b * LC + i];
#pragma unroll
    for (int v = 0; v < 8; ++v) {
      int j = j0 + emap(tx4, v);
      S[((size_t)b * LC + i) * LQ + j] = acc[u][v] + ra + qw2[b * LQ + j];
    }
  }
}

// ---------------- row softmax over j (qmask) -> S1 (bf16) ----------------
__global__ void k_rowsoftmax(const float* __restrict__ S, const float* __restrict__ qmask,
                             bf16* __restrict__ S1, int* __restrict__ flags) {
  const int wid = threadIdx.x >> 6, lane = threadIdx.x & 63;
  const int row = blockIdx.x * 4 + wid;
  const int b = row >> 10;
  const float* Srow = S + (size_t)row * LQ;
  const float* qm = qmask + b * LQ;
  float logit[8];
  float m = -3e38f;
  int bad = 0;
#pragma unroll
  for (int tt = 0; tt < 8; ++tt) {
    int j = lane + 64 * tt;
    float sv = Srow[j];
    if (!(fabsf(sv) < 1e20f)) { bad = 1; sv = NEGINF; }
    float mk = qm[j];
    logit[tt] = mk * sv + (1.f - mk) * NEGINF;
    m = fmaxf(m, logit[tt]);
  }
#pragma unroll
  for (int off = 32; off; off >>= 1) m = fmaxf(m, __shfl_xor(m, off, 64));
  float e[8];
  float s = 0.f;
#pragma unroll
  for (int tt = 0; tt < 8; ++tt) { e[tt] = __expf(logit[tt] - m); s += e[tt]; }
#pragma unroll
  for (int off = 32; off; off >>= 1) s += __shfl_xor(s, off, 64);
  float inv = 1.f / s;
  bf16* Orow = S1 + (size_t)row * LQ;
#pragma unroll
  for (int tt = 0; tt < 8; ++tt) Orow[lane + 64 * tt] = f2b(e[tt] * inv);
  if (bad) atomicOr(flags, 2);
}

// ---------------- col softmax over i (cmask) -> S2 (bf16) ----------------
__global__ void k_colsoftmax(const float* __restrict__ S, const float* __restrict__ cmask,
                             bf16* __restrict__ S2, int* __restrict__ flags) {
  __shared__ float sm[4][64], ss[4][64];
  const int b = blockIdx.y;
  const int j0 = blockIdx.x * 64;
  const int c = threadIdx.x & 63, r4 = threadIdx.x >> 6;
  const float* Sb = S + (size_t)b * LC * LQ;
  const float* cm = cmask + b * LC;
  float m = -3e38f, s = 0.f;
  int bad = 0;
  for (int i = r4; i < LC; i += 4) {
    float sv = Sb[(size_t)i * LQ + j0 + c];
    if (!(fabsf(sv) < 1e20f)) { bad = 1; sv = NEGINF; }
    float mk = cm[i];
    float logit = mk * sv + (1.f - mk) * NEGINF;
    if (logit > m) { s *= __expf(m - logit); m = logit; }
    s += __expf(logit - m);
  }
  sm[r4][c] = m; ss[r4][c] = s;
  __syncthreads();
  if (r4 == 0) {
    float M = m, Sd = s;
#pragma unroll
    for (int r = 1; r < 4; ++r) {
      float mr = sm[r][c], sr = ss[r][c];
      float nM = fmaxf(M, mr);
      Sd = Sd * __expf(M - nM) + sr * __expf(mr - nM);
      M = nM;
    }
    sm[0][c] = M; ss[0][c] = 1.f / Sd;
  }
  __syncthreads();
  const float M = sm[0][c], inv = ss[0][c];
  bf16* S2b = S2 + (size_t)b * LC * LQ;
  for (int i = r4; i < LC; i += 4) {
    float sv = Sb[(size_t)i * LQ + j0 + c];
    if (!(fabsf(sv) < 1e20f)) sv = NEGINF;
    float mk = cm[i];
    float logit = mk * sv + (1.f - mk) * NEGINF;
    S2b[(size_t)i * LQ + j0 + c] = f2b(__expf(logit - M) * inv);
  }
  if (bad) atomicOr(flags, 2);
}

// ---------------- G2: A = S1 @ Q  (M=LC, N=DM, K=LQ) ----------------
__global__ void k_gemm_A(const bf16* __restrict__ S1, const float* __restrict__ Q,
                         bf16* __restrict__ Aw) {
  __shared__ float As[8][132], Bs[8][132];
  const int b = blockIdx.z;
  const int i0 = blockIdx.y * 128, n0 = blockIdx.x * 128;
  const bf16*  S1b = S1 + (size_t)b * LC * LQ;
  const float* Qb  = Q  + (size_t)b * LQ * DM;
  const int t = threadIdx.x;
  const int tx4 = (t & 15) * 4, ty4 = (t >> 4) * 4;
  const int lr = t >> 1, lc4 = (t & 1) * 4;
  const int kr = t >> 5, nc4 = (t & 31) * 4;
  float acc[8][8];
#pragma unroll
  for (int u = 0; u < 8; ++u)
#pragma unroll
    for (int v = 0; v < 8; ++v) acc[u][v] = 0.f;

  for (int k0 = 0; k0 < LQ; k0 += 8) {
#pragma unroll
    for (int u = 0; u < 4; ++u) {
      As[lc4 + u][lr]  = b2f(S1b[(size_t)(i0 + lr) * LQ + k0 + lc4 + u]);
      Bs[kr][nc4 + u]  = Qb[(size_t)(k0 + kr) * DM + n0 + nc4 + u];
    }
    __syncthreads();
    mm8x8(As, Bs, acc, tx4, ty4);
    __syncthreads();
  }
#pragma unroll
  for (int u = 0; u < 8; ++u) {
    int i = i0 + emap(ty4, u);
#pragma unroll
    for (int v = 0; v < 8; ++v) {
      int n = n0 + emap(tx4, v);
      Aw[((size_t)b * LC + i) * DM + n] = f2b(acc[u][v]);
    }
  }
}

// ---------------- G3: S2TC = S2^T @ C  (M=LQ(j), N=DM, K=LC(i)) ----------------
__global__ void k_gemm_S2TC(const bf16* __restrict__ S2, const float* __restrict__ C,
                            bf16* __restrict__ S2TC) {
  __shared__ float As[8][132], Bs[8][132];
  const int b = blockIdx.z;
  const int j0 = blockIdx.y * 128, n0 = blockIdx.x * 128;
  const bf16*  S2b = S2 + (size_t)b * LC * LQ;
  const float* Cb  = C  + (size_t)b * LC * DM;
  const int t = threadIdx.x;
  const int tx4 = (t & 15) * 4, ty4 = (t >> 4) * 4;
  const int kr = t >> 5, nc4 = (t & 31) * 4;
  float acc[8][8];
#pragma unroll
  for (int u = 0; u < 8; ++u)
#pragma unroll
    for (int v = 0; v < 8; ++v) acc[u][v] = 0.f;

  for (int k0 = 0; k0 < LC; k0 += 8) {
#pragma unroll
    for (int u = 0; u < 4; ++u) {
      As[kr][nc4 + u] = b2f(S2b[(size_t)(k0 + kr) * LQ + j0 + nc4 + u]);
      Bs[kr][nc4 + u] = Cb[(size_t)(k0 + kr) * DM + n0 + nc4 + u];
    }
    __syncthreads();
    mm8x8(As, Bs, acc, tx4, ty4);
    __syncthreads();
  }
#pragma unroll
  for (int u = 0; u < 8; ++u) {
    int j = j0 + emap(ty4, u);
#pragma unroll
    for (int v = 0; v < 8; ++v) {
      int n = n0 + emap(tx4, v);
      S2TC[((size_t)b * LQ + j) * DM + n] = f2b(acc[u][v]);
    }
  }
}

// ---------------- G4: Bm = S1 @ S2TC  (M=LC, N=DM, K=LQ) ----------------
__global__ void k_gemm_Bm(const bf16* __restrict__ S1, const bf16* __restrict__ S2TC,
                          bf16* __restrict__ Bmw) {
  __shared__ float As[8][132], Bs[8][132];
  const int b = blockIdx.z;
  const int i0 = blockIdx.y * 128, n0 = blockIdx.x * 128;
  const bf16* S1b = S1 + (size_t)b * LC * LQ;
  const bf16* Tb  = S2TC + (size_t)b * LQ * DM;
  const int t = threadIdx.x;
  const int tx4 = (t & 15) * 4, ty4 = (t >> 4) * 4;
  const int lr = t >> 1, lc4 = (t & 1) * 4;
  const int kr = t >> 5, nc4 = (t & 31) * 4;
  float acc[8][8];
#pragma unroll
  for (int u = 0; u < 8; ++u)
#pragma unroll
    for (int v = 0; v < 8; ++v) acc[u][v] = 0.f;

  for (int k0 = 0; k0 < LQ; k0 += 8) {
#pragma unroll
    for (int u = 0; u < 4; ++u) {
      As[lc4 + u][lr] = b2f(S1b[(size_t)(i0 + lr) * LQ + k0 + lc4 + u]);
      Bs[kr][nc4 + u] = b2f(Tb[(size_t)(k0 + kr) * DM + n0 + nc4 + u]);
    }
    __syncthreads();
    mm8x8(As, Bs, acc, tx4, ty4);
    __syncthreads();
  }
#pragma unroll
  for (int u = 0; u < 8; ++u) {
    int i = i0 + emap(ty4, u);
#pragma unroll
    for (int v = 0; v < 8; ++v) {
      int n = n0 + emap(tx4, v);
      Bmw[((size_t)b * LC + i) * DM + n] = f2b(acc[u][v]);
    }
  }
}

// -------- G5: out = [C, A, C*A, C*Bm] @ out_w^T + out_b ----------
__global__ void k_gemm_out(const float* __restrict__ C, const bf16* __restrict__ Aw,
                           const bf16* __restrict__ Bmw, const float* __restrict__ out_w,
                           const float* __restrict__ out_b, float* __restrict__ out) {
  __shared__ float As[8][132], Bs[8][132];
  const int b = blockIdx.z;
  const int i0 = blockIdx.y * 128, n0 = blockIdx.x * 128;
  const float* Cb = C   + (size_t)b * LC * DM;
  const bf16*  Ab = Aw  + (size_t)b * LC * DM;
  const bf16*  Bb = Bmw + (size_t)b * LC * DM;
  const int t = threadIdx.x;
  const int tx4 = (t & 15) * 4, ty4 = (t >> 4) * 4;
  const int lr = t >> 1, lc4 = (t & 1) * 4;
  float acc[8][8];
#pragma unroll
  for (int u = 0; u < 8; ++u)
#pragma unroll
    for (int v = 0; v < 8; ++v) acc[u][v] = 0.f;

  for (int k0 = 0; k0 < D4; k0 += 8) {
    const int seg = k0 >> 9;
    const int kl0 = (k0 & 511) + lc4;
#pragma unroll
    for (int u = 0; u < 4; ++u) {
      size_t idx = (size_t)(i0 + lr) * DM + kl0 + u;
      float av;
      if (seg == 0)      av = Cb[idx];
      else if (seg == 1) av = b2f(Ab[idx]);
      else if (seg == 2) av = Cb[idx] * b2f(Ab[idx]);
      else               av = Cb[idx] * b2f(Bb[idx]);
      As[lc4 + u][lr] = av;
      Bs[lc4 + u][lr] = out_w[(size_t)(n0 + lr) * D4 + k0 + lc4 + u];
    }
    __syncthreads();
    mm8x8(As, Bs, acc, tx4, ty4);
    __syncthreads();
  }
#pragma unroll
  for (int u = 0; u < 8; ++u) {
    int i = i0 + emap(ty4, u);
#pragma unroll
    for (int v = 0; v < 8; ++v) {
      int n = n0 + emap(tx4, v);
      out[((size_t)b * LC + i) * DM + n] = acc[u][v] + out_b[n];
    }
  }
}

extern "C" void kernel_launch(void* const* d_in, const int* in_sizes, int n_in,
                              void* d_out, int out_size, void* d_ws, size_t ws_size,
                              hipStream_t stream) {
  const float* C     = (const float*)d_in[0];
  const float* Q     = (const float*)d_in[1];
  const float* cmask = (const float*)d_in[2];
  const float* qmask = (const float*)d_in[3];
  const float* w     = (const float*)d_in[4];
  const float* out_w = (const float*)d_in[5];
  const float* out_b = (const float*)d_in[6];
  float* out = (float*)d_out;

  // ---- workspace carve (aliased; 72 MiB + 128 KiB; confirmed available) ----
  char* base = (char*)d_ws;
  int*   flags = (int*)base;                                   // [0,256)
  float* cw1   = (float*)(base + 256);                         // 64 KiB
  float* qw2   = (float*)(base + 256 + 65536);                 // 32 KiB
  char*  R0    = base + 131072;                                // 32 MiB: S, later Aw+Bmw
  float* S     = (float*)R0;
  bf16*  Aw    = (bf16*)R0;                                    // aliases S[0:16Mi)
  bf16*  Bmw   = (bf16*)(R0 + (32u << 20) / 2);                // aliases S[16Mi:32Mi)
  bf16*  S1    = (bf16*)(base + 131072 + (32u << 20));         // 16 MiB
  bf16*  S2    = (bf16*)(base + 131072 + (48u << 20));         // 16 MiB
  bf16*  S2TC  = (bf16*)(base + 131072 + (64u << 20));         //  8 MiB
  const size_t WS_NEED = 131072 + (72u << 20);

  int hostflags = 0;
  if (n_in != 7 ||
      in_sizes[0] != NB * LC * DM || in_sizes[1] != NB * LQ * DM ||
      in_sizes[2] != NB * LC      || in_sizes[3] != NB * LQ ||
      in_sizes[4] != 3 * DM       || in_sizes[5] != DM * D4 ||
      in_sizes[6] != DM           || out_size != NB * LC * DM)
    hostflags |= 8;
  if (ws_size < WS_NEED) hostflags |= 16;

  k_zeroflags<<<1, 1, 0, stream>>>(flags);
  for (int i = 0; i < n_in && i < 7; ++i)
    k_scan_f32<<<2048, 256, 0, stream>>>((const unsigned int*)d_in[i], (long)in_sizes[i], flags);

  if (hostflags == 0) {
    k_rowdots<<<(NB * LC + NB * LQ) / 4, 256, 0, stream>>>(C, Q, w, cw1, qw2);
    k_gemm_S<<<dim3(LQ / 128, LC / 128, NB), 256, 0, stream>>>(C, Q, w, cw1, qw2, S);
    k_rowsoftmax<<<NB * LC / 4, 256, 0, stream>>>(S, qmask, S1, flags);
    k_colsoftmax<<<dim3(LQ / 64, NB), 256, 0, stream>>>(S, cmask, S2, flags);
    k_gemm_A<<<dim3(DM / 128, LC / 128, NB), 256, 0, stream>>>(S1, Q, Aw);
    k_gemm_S2TC<<<dim3(DM / 128, LQ / 128, NB), 256, 0, stream>>>(S2, C, S2TC);
    k_gemm_Bm<<<dim3(DM / 128, LC / 128, NB), 256, 0, stream>>>(S1, S2TC, Bmw);
    k_gemm_out<<<dim3(DM / 128, LC / 128, NB), 256, 0, stream>>>(C, Aw, Bmw, out_w, out_b, out);
  }
  k_finalize<<<1, 1, 0, stream>>>(flags, hostflags, out);
}

// Round 4
// 523.554 us; speedup vs baseline: 3.1510x; 3.1510x over previous
//
#include <hip/hip_runtime.h>
#include <hip/hip_bf16.h>

// CQAttention: B=16, Lc=1024, Lq=512, d=512.  f32 I/O, bf16 MFMA GEMMs, f32 acc.
// Round 4: all five GEMMs on mfma_f32_16x16x32_bf16. 128x128 tile, 4 waves of
// 64x64 (4x4 16x16 tiles), BK=32, LDS rows padded to 40 bf16 (b128 frag reads
// 2-way conflict = free). f32->bf16 conversion inline during staging; operand
// transposes done in LDS staging. ws = 72 MiB aliased (validated round 3).

#define NB 16
#define LC 1024
#define LQ 512
#define DM 512
#define D4 2048
#define NEGINF (-1e30f)
#define BK 32
#define LDAp 40   // padded LDS k-stride (bf16 elems)

typedef __bf16 v8bf __attribute__((ext_vector_type(8)));
typedef __bf16 v4bf __attribute__((ext_vector_type(4)));
typedef float  v4f  __attribute__((ext_vector_type(4)));

#define MFMA16 __builtin_amdgcn_mfma_f32_16x16x32_bf16

#define TILE_SETUP \
  const int t = threadIdx.x, lane = t & 63, wave = t >> 6; \
  const int wm = wave >> 1, wn = wave & 1, quad = lane >> 4, col = lane & 15;

#define ZERO_ACC \
  v4f acc[4][4]; \
  _Pragma("unroll") for (int x = 0; x < 4; ++x) \
  _Pragma("unroll") for (int y = 0; y < 4; ++y) \
  _Pragma("unroll") for (int r = 0; r < 4; ++r) acc[x][y][r] = 0.f;

// frag reads + 16 MFMAs on staged LDS tiles
#define FRAG_MMA(AL, BL) do { \
  v8bf af_[4], bf_[4]; \
  _Pragma("unroll") for (int x = 0; x < 4; ++x) \
    af_[x] = *(const v8bf*)&AL[(wm * 64 + x * 16 + col) * LDAp + quad * 8]; \
  _Pragma("unroll") for (int y = 0; y < 4; ++y) \
    bf_[y] = *(const v8bf*)&BL[(wn * 64 + y * 16 + col) * LDAp + quad * 8]; \
  _Pragma("unroll") for (int x = 0; x < 4; ++x) \
  _Pragma("unroll") for (int y = 0; y < 4; ++y) \
    acc[x][y] = MFMA16(af_[x], bf_[y], acc[x][y], 0, 0, 0); \
} while (0)

// ---------------- K1: cw1[b,i] = C.w1, qw2[b,j] = Q.w2 ----------------
__global__ void k_rowdots(const float* __restrict__ C, const float* __restrict__ Q,
                          const float* __restrict__ w,
                          float* __restrict__ cw1, float* __restrict__ qw2) {
  const int wid = threadIdx.x >> 6, lane = threadIdx.x & 63;
  const int row = blockIdx.x * 4 + wid;
  const bool isC = row < NB * LC;
  const float* src = isC ? (C + (size_t)row * DM) : (Q + (size_t)(row - NB * LC) * DM);
  const float* wv  = isC ? w : (w + DM);
  float v = 0.f;
#pragma unroll
  for (int tt = 0; tt < 8; ++tt) {
    int k = lane + 64 * tt;
    v += src[k] * wv[k];
  }
#pragma unroll
  for (int off = 32; off; off >>= 1) v += __shfl_down(v, off, 64);
  if (lane == 0) {
    if (isC) cw1[row] = v;
    else     qw2[row - NB * LC] = v;
  }
}

// ---------------- G1: S = cw1 + qw2 + (C*w3) @ Q^T  (M=Lc, N=Lq, K=DM) --------
__global__ __launch_bounds__(256) void k_mfma_S(
    const float* __restrict__ C, const float* __restrict__ Q, const float* __restrict__ w,
    const float* __restrict__ cw1, const float* __restrict__ qw2, float* __restrict__ S) {
  __shared__ __bf16 Al[128 * LDAp], Bl[128 * LDAp];
  const int b = blockIdx.z, i0 = blockIdx.y * 128, j0 = blockIdx.x * 128;
  TILE_SETUP
  const float* Cb = C + (size_t)b * LC * DM;
  const float* Qb = Q + (size_t)b * LQ * DM;
  const float* w3 = w + 2 * DM;
  const int sr = t >> 1, skc = (t & 1) * 16;   // stage: 2 thr/row, 16 k each
  ZERO_ACC
  for (int k0 = 0; k0 < DM; k0 += BK) {
    const float* ca = Cb + (size_t)(i0 + sr) * DM + k0 + skc;
    const float* qa = Qb + (size_t)(j0 + sr) * DM + k0 + skc;
    const float* wa = w3 + k0 + skc;
#pragma unroll
    for (int u = 0; u < 4; ++u) {
      float4 cf = *(const float4*)(ca + 4 * u);
      float4 wf = *(const float4*)(wa + 4 * u);
      float4 qf = *(const float4*)(qa + 4 * u);
      v4bf ah, bh;
      ah[0] = (__bf16)(cf.x * wf.x); ah[1] = (__bf16)(cf.y * wf.y);
      ah[2] = (__bf16)(cf.z * wf.z); ah[3] = (__bf16)(cf.w * wf.w);
      bh[0] = (__bf16)qf.x; bh[1] = (__bf16)qf.y; bh[2] = (__bf16)qf.z; bh[3] = (__bf16)qf.w;
      *(v4bf*)&Al[sr * LDAp + skc + 4 * u] = ah;
      *(v4bf*)&Bl[sr * LDAp + skc + 4 * u] = bh;
    }
    __syncthreads();
    FRAG_MMA(Al, Bl);
    __syncthreads();
  }
  float* Sb = S + (size_t)b * LC * LQ;
#pragma unroll
  for (int x = 0; x < 4; ++x) {
    const int mB = i0 + wm * 64 + x * 16 + quad * 4;
    float cv[4];
#pragma unroll
    for (int r = 0; r < 4; ++r) cv[r] = cw1[b * LC + mB + r];
#pragma unroll
    for (int y = 0; y < 4; ++y) {
      const int j = j0 + wn * 64 + y * 16 + col;
      const float qv = qw2[b * LQ + j];
#pragma unroll
      for (int r = 0; r < 4; ++r)
        Sb[(size_t)(mB + r) * LQ + j] = acc[x][y][r] + cv[r] + qv;
    }
  }
}

// ---------------- row softmax over j (qmask) -> S1 bf16 ----------------
__global__ void k_rowsoftmax(const float* __restrict__ S, const float* __restrict__ qmask,
                             __bf16* __restrict__ S1) {
  const int wid = threadIdx.x >> 6, lane = threadIdx.x & 63;
  const int row = blockIdx.x * 4 + wid;
  const int b = row >> 10;
  const float* Srow = S + (size_t)row * LQ;
  const float* qm = qmask + b * LQ;
  float logit[8];
  float m = -3e38f;
#pragma unroll
  for (int tt = 0; tt < 8; ++tt) {
    int j = lane + 64 * tt;
    float mk = qm[j];
    logit[tt] = mk * Srow[j] + (1.f - mk) * NEGINF;
    m = fmaxf(m, logit[tt]);
  }
#pragma unroll
  for (int off = 32; off; off >>= 1) m = fmaxf(m, __shfl_xor(m, off, 64));
  float e[8];
  float s = 0.f;
#pragma unroll
  for (int tt = 0; tt < 8; ++tt) { e[tt] = __expf(logit[tt] - m); s += e[tt]; }
#pragma unroll
  for (int off = 32; off; off >>= 1) s += __shfl_xor(s, off, 64);
  float inv = 1.f / s;
  __bf16* Orow = S1 + (size_t)row * LQ;
#pragma unroll
  for (int tt = 0; tt < 8; ++tt) Orow[lane + 64 * tt] = (__bf16)(e[tt] * inv);
}

// ---------------- col softmax over i (cmask) -> S2 bf16 [i][j] ----------------
__global__ void k_colsoftmax(const float* __restrict__ S, const float* __restrict__ cmask,
                             __bf16* __restrict__ S2) {
  __shared__ float sm[4][64], ss[4][64];
  const int b = blockIdx.y;
  const int j0 = blockIdx.x * 64;
  const int c = threadIdx.x & 63, r4 = threadIdx.x >> 6;
  const float* Sb = S + (size_t)b * LC * LQ;
  const float* cm = cmask + b * LC;
  float m = -3e38f, s = 0.f;
  for (int i = r4; i < LC; i += 4) {
    float mk = cm[i];
    float logit = mk * Sb[(size_t)i * LQ + j0 + c] + (1.f - mk) * NEGINF;
    if (logit > m) { s *= __expf(m - logit); m = logit; }
    s += __expf(logit - m);
  }
  sm[r4][c] = m; ss[r4][c] = s;
  __syncthreads();
  if (r4 == 0) {
    float M = m, Sd = s;
#pragma unroll
    for (int r = 1; r < 4; ++r) {
      float mr = sm[r][c], sr = ss[r][c];
      float nM = fmaxf(M, mr);
      Sd = Sd * __expf(M - nM) + sr * __expf(mr - nM);
      M = nM;
    }
    sm[0][c] = M; ss[0][c] = 1.f / Sd;
  }
  __syncthreads();
  const float M = sm[0][c], inv = ss[0][c];
  __bf16* S2b = S2 + (size_t)b * LC * LQ;
  for (int i = r4; i < LC; i += 4) {
    float mk = cm[i];
    float logit = mk * Sb[(size_t)i * LQ + j0 + c] + (1.f - mk) * NEGINF;
    S2b[(size_t)i * LQ + j0 + c] = (__bf16)(__expf(logit - M) * inv);
  }
}

// ---------------- G2: A = S1 @ Q  (M=Lc, N=DM, K=Lq; B=Q^T staged) ------------
__global__ __launch_bounds__(256) void k_mfma_A(
    const __bf16* __restrict__ S1, const float* __restrict__ Q, __bf16* __restrict__ Aw) {
  __shared__ __bf16 Al[128 * LDAp], Bl[128 * LDAp];
  const int b = blockIdx.z, i0 = blockIdx.y * 128, n0 = blockIdx.x * 128;
  TILE_SETUP
  const __bf16* S1b = S1 + (size_t)b * LC * LQ;
  const float*  Qb  = Q  + (size_t)b * LQ * DM;
  const int ar = t >> 1, akc = (t & 1) * 16;   // A direct
  const int kk = t >> 3, nn = (t & 7) * 16;    // B transpose
  ZERO_ACC
  for (int k0 = 0; k0 < LQ; k0 += BK) {
    const __bf16* sa = S1b + (size_t)(i0 + ar) * LQ + k0 + akc;
#pragma unroll
    for (int u = 0; u < 2; ++u)
      *(v8bf*)&Al[ar * LDAp + akc + 8 * u] = *(const v8bf*)(sa + 8 * u);
    const float* qa = Qb + (size_t)(k0 + kk) * DM + n0 + nn;
#pragma unroll
    for (int u = 0; u < 4; ++u) {
      float4 f = *(const float4*)(qa + 4 * u);
      Bl[(nn + 4 * u + 0) * LDAp + kk] = (__bf16)f.x;
      Bl[(nn + 4 * u + 1) * LDAp + kk] = (__bf16)f.y;
      Bl[(nn + 4 * u + 2) * LDAp + kk] = (__bf16)f.z;
      Bl[(nn + 4 * u + 3) * LDAp + kk] = (__bf16)f.w;
    }
    __syncthreads();
    FRAG_MMA(Al, Bl);
    __syncthreads();
  }
  __bf16* Ab = Aw + (size_t)b * LC * DM;
#pragma unroll
  for (int x = 0; x < 4; ++x) {
    const int mB = i0 + wm * 64 + x * 16 + quad * 4;
#pragma unroll
    for (int y = 0; y < 4; ++y) {
      const int n = n0 + wn * 64 + y * 16 + col;
#pragma unroll
      for (int r = 0; r < 4; ++r)
        Ab[(size_t)(mB + r) * DM + n] = (__bf16)acc[x][y][r];
    }
  }
}

// ------- G3: S2TC^T[n][j] = (S2^T @ C)^T  (M=Lq(j), N=DM, K=Lc(i)) -----------
__global__ __launch_bounds__(256) void k_mfma_T(
    const __bf16* __restrict__ S2, const float* __restrict__ C, __bf16* __restrict__ S2TCT) {
  __shared__ __bf16 Al[128 * LDAp], Bl[128 * LDAp];
  const int b = blockIdx.z, j0 = blockIdx.y * 128, n0 = blockIdx.x * 128;
  TILE_SETUP
  const __bf16* S2b = S2 + (size_t)b * LC * LQ;
  const float*  Cb  = C  + (size_t)b * LC * DM;
  const int kk = t >> 3, jj = (t & 7) * 16;    // both operands transpose-staged
  ZERO_ACC
  for (int k0 = 0; k0 < LC; k0 += BK) {
    const __bf16* sa = S2b + (size_t)(k0 + kk) * LQ + j0 + jj;
    v8bf s0 = *(const v8bf*)(sa), s1 = *(const v8bf*)(sa + 8);
#pragma unroll
    for (int u = 0; u < 8; ++u) {
      Al[(jj + u) * LDAp + kk]     = s0[u];
      Al[(jj + 8 + u) * LDAp + kk] = s1[u];
    }
    const float* cb2 = Cb + (size_t)(k0 + kk) * DM + n0 + jj;
#pragma unroll
    for (int u = 0; u < 4; ++u) {
      float4 f = *(const float4*)(cb2 + 4 * u);
      Bl[(jj + 4 * u + 0) * LDAp + kk] = (__bf16)f.x;
      Bl[(jj + 4 * u + 1) * LDAp + kk] = (__bf16)f.y;
      Bl[(jj + 4 * u + 2) * LDAp + kk] = (__bf16)f.z;
      Bl[(jj + 4 * u + 3) * LDAp + kk] = (__bf16)f.w;
    }
    __syncthreads();
    FRAG_MMA(Al, Bl);
    __syncthreads();
  }
  // store transposed: S2TCT[b][n][j]
#pragma unroll
  for (int x = 0; x < 4; ++x) {
    const int jB = j0 + wm * 64 + x * 16 + quad * 4;
#pragma unroll
    for (int y = 0; y < 4; ++y) {
      const int n = n0 + wn * 64 + y * 16 + col;
      v4bf h;
#pragma unroll
      for (int r = 0; r < 4; ++r) h[r] = (__bf16)acc[x][y][r];
      *(v4bf*)&S2TCT[((size_t)b * DM + n) * LQ + jB] = h;
    }
  }
}

// ---------------- G4: Bm = S1 @ S2TC  (B = S2TCT direct) ----------------
__global__ __launch_bounds__(256) void k_mfma_Bm(
    const __bf16* __restrict__ S1, const __bf16* __restrict__ S2TCT, __bf16* __restrict__ Bmw) {
  __shared__ __bf16 Al[128 * LDAp], Bl[128 * LDAp];
  const int b = blockIdx.z, i0 = blockIdx.y * 128, n0 = blockIdx.x * 128;
  TILE_SETUP
  const __bf16* S1b = S1 + (size_t)b * LC * LQ;
  const __bf16* Tb  = S2TCT + (size_t)b * DM * LQ;
  const int ar = t >> 1, akc = (t & 1) * 16;
  ZERO_ACC
  for (int k0 = 0; k0 < LQ; k0 += BK) {
    const __bf16* sa = S1b + (size_t)(i0 + ar) * LQ + k0 + akc;
    const __bf16* ta = Tb + (size_t)(n0 + ar) * LQ + k0 + akc;
#pragma unroll
    for (int u = 0; u < 2; ++u) {
      *(v8bf*)&Al[ar * LDAp + akc + 8 * u] = *(const v8bf*)(sa + 8 * u);
      *(v8bf*)&Bl[ar * LDAp + akc + 8 * u] = *(const v8bf*)(ta + 8 * u);
    }
    __syncthreads();
    FRAG_MMA(Al, Bl);
    __syncthreads();
  }
  __bf16* Bb = Bmw + (size_t)b * LC * DM;
#pragma unroll
  for (int x = 0; x < 4; ++x) {
    const int mB = i0 + wm * 64 + x * 16 + quad * 4;
#pragma unroll
    for (int y = 0; y < 4; ++y) {
      const int n = n0 + wn * 64 + y * 16 + col;
#pragma unroll
      for (int r = 0; r < 4; ++r)
        Bb[(size_t)(mB + r) * DM + n] = (__bf16)acc[x][y][r];
    }
  }
}

// -------- G5: out = [C, A, C*A, C*Bm] @ out_w^T + out_b  (K=2048) ------------
__global__ __launch_bounds__(256) void k_mfma_out(
    const float* __restrict__ C, const __bf16* __restrict__ Aw, const __bf16* __restrict__ Bmw,
    const float* __restrict__ OW, const float* __restrict__ ob, float* __restrict__ out) {
  __shared__ __bf16 Al[128 * LDAp], Bl[128 * LDAp];
  const int b = blockIdx.z, i0 = blockIdx.y * 128, n0 = blockIdx.x * 128;
  TILE_SETUP
  const float*  Cb  = C   + (size_t)b * LC * DM;
  const __bf16* Ab  = Aw  + (size_t)b * LC * DM;
  const __bf16* Bb  = Bmw + (size_t)b * LC * DM;
  const int ar = t >> 1, akc = (t & 1) * 16;
  ZERO_ACC
  for (int k0 = 0; k0 < D4; k0 += BK) {
    const int seg = k0 >> 9;
    const int kl = (k0 & 511) + akc;
    const float*  cr = Cb + (size_t)(i0 + ar) * DM + kl;
    if (seg == 0) {
#pragma unroll
      for (int u = 0; u < 4; ++u) {
        float4 f = *(const float4*)(cr + 4 * u);
        v4bf h; h[0] = (__bf16)f.x; h[1] = (__bf16)f.y; h[2] = (__bf16)f.z; h[3] = (__bf16)f.w;
        *(v4bf*)&Al[ar * LDAp + akc + 4 * u] = h;
      }
    } else if (seg == 1) {
      const __bf16* ap = Ab + (size_t)(i0 + ar) * DM + kl;
#pragma unroll
      for (int u = 0; u < 2; ++u)
        *(v8bf*)&Al[ar * LDAp + akc + 8 * u] = *(const v8bf*)(ap + 8 * u);
    } else if (seg == 2) {
      const __bf16* ap = Ab + (size_t)(i0 + ar) * DM + kl;
#pragma unroll
      for (int u = 0; u < 2; ++u) {
        v8bf av = *(const v8bf*)(ap + 8 * u);
        float4 f0 = *(const float4*)(cr + 8 * u);
        float4 f1 = *(const float4*)(cr + 8 * u + 4);
        v8bf h;
        h[0] = (__bf16)(f0.x * (float)av[0]); h[1] = (__bf16)(f0.y * (float)av[1]);
        h[2] = (__bf16)(f0.z * (float)av[2]); h[3] = (__bf16)(f0.w * (float)av[3]);
        h[4] = (__bf16)(f1.x * (float)av[4]); h[5] = (__bf16)(f1.y * (float)av[5]);
        h[6] = (__bf16)(f1.z * (float)av[6]); h[7] = (__bf16)(f1.w * (float)av[7]);
        *(v8bf*)&Al[ar * LDAp + akc + 8 * u] = h;
      }
    } else {
      const __bf16* bp = Bb + (size_t)(i0 + ar) * DM + kl;
#pragma unroll
      for (int u = 0; u < 2; ++u) {
        v8bf bv = *(const v8bf*)(bp + 8 * u);
        float4 f0 = *(const float4*)(cr + 8 * u);
        float4 f1 = *(const float4*)(cr + 8 * u + 4);
        v8bf h;
        h[0] = (__bf16)(f0.x * (float)bv[0]); h[1] = (__bf16)(f0.y * (float)bv[1]);
        h[2] = (__bf16)(f0.z * (float)bv[2]); h[3] = (__bf16)(f0.w * (float)bv[3]);
        h[4] = (__bf16)(f1.x * (float)bv[4]); h[5] = (__bf16)(f1.y * (float)bv[5]);
        h[6] = (__bf16)(f1.z * (float)bv[6]); h[7] = (__bf16)(f1.w * (float)bv[7]);
        *(v8bf*)&Al[ar * LDAp + akc + 8 * u] = h;
      }
    }
    const float* owr = OW + (size_t)(n0 + ar) * D4 + k0 + akc;
#pragma unroll
    for (int u = 0; u < 4; ++u) {
      float4 f = *(const float4*)(owr + 4 * u);
      v4bf h; h[0] = (__bf16)f.x; h[1] = (__bf16)f.y; h[2] = (__bf16)f.z; h[3] = (__bf16)f.w;
      *(v4bf*)&Bl[ar * LDAp + akc + 4 * u] = h;
    }
    __syncthreads();
    FRAG_MMA(Al, Bl);
    __syncthreads();
  }
  float* outb = out + (size_t)b * LC * DM;
#pragma unroll
  for (int x = 0; x < 4; ++x) {
    const int mB = i0 + wm * 64 + x * 16 + quad * 4;
#pragma unroll
    for (int y = 0; y < 4; ++y) {
      const int n = n0 + wn * 64 + y * 16 + col;
      const float bv = ob[n];
#pragma unroll
      for (int r = 0; r < 4; ++r)
        outb[(size_t)(mB + r) * DM + n] = acc[x][y][r] + bv;
    }
  }
}

extern "C" void kernel_launch(void* const* d_in, const int* in_sizes, int n_in,
                              void* d_out, int out_size, void* d_ws, size_t ws_size,
                              hipStream_t stream) {
  const float* C     = (const float*)d_in[0];
  const float* Q     = (const float*)d_in[1];
  const float* cmask = (const float*)d_in[2];
  const float* qmask = (const float*)d_in[3];
  const float* w     = (const float*)d_in[4];
  const float* out_w = (const float*)d_in[5];
  const float* out_b = (const float*)d_in[6];
  float* out = (float*)d_out;

  // ---- workspace carve (72 MiB + 128 KiB; validated in round 3) ----
  char* base = (char*)d_ws;
  float*  cw1   = (float*)base;                                // 64 KiB
  float*  qw2   = (float*)(base + 65536);                      // 32 KiB
  char*   R     = base + 131072;
  float*  S     = (float*)R;                                   // 32 MiB (f32 scores)
  __bf16* Aw    = (__bf16*)R;                                  // alias S[0:16Mi)
  __bf16* Bmw   = (__bf16*)(R + (16u << 20));                  // alias S[16Mi:32Mi)
  __bf16* S1    = (__bf16*)(base + 131072 + (32u << 20));      // 16 MiB
  __bf16* S2    = (__bf16*)(base + 131072 + (48u << 20));      // 16 MiB
  __bf16* S2TCT = (__bf16*)(base + 131072 + (64u << 20));      //  8 MiB
  (void)in_sizes; (void)n_in; (void)out_size; (void)ws_size;

  k_rowdots<<<(NB * LC + NB * LQ) / 4, 256, 0, stream>>>(C, Q, w, cw1, qw2);
  k_mfma_S<<<dim3(LQ / 128, LC / 128, NB), 256, 0, stream>>>(C, Q, w, cw1, qw2, S);
  k_rowsoftmax<<<NB * LC / 4, 256, 0, stream>>>(S, qmask, S1);
  k_colsoftmax<<<dim3(LQ / 64, NB), 256, 0, stream>>>(S, cmask, S2);
  k_mfma_A<<<dim3(DM / 128, LC / 128, NB), 256, 0, stream>>>(S1, Q, Aw);
  k_mfma_T<<<dim3(DM / 128, LQ / 128, NB), 256, 0, stream>>>(S2, C, S2TCT);
  k_mfma_Bm<<<dim3(DM / 128, LC / 128, NB), 256, 0, stream>>>(S1, S2TCT, Bmw);
  k_mfma_out<<<dim3(DM / 128, LC / 128, NB), 256, 0, stream>>>(C, Aw, Bmw, out_w, out_b, out);
}

// Round 5
// 394.285 us; speedup vs baseline: 4.1840x; 1.3279x over previous
//
#include <hip/hip_runtime.h>
#include <hip/hip_bf16.h>

// CQAttention: B=16, Lc=1024, Lq=512, d=512.  f32 I/O, bf16 MFMA GEMMs, f32 acc.
// Round 5: colsoftmax restructured from 128-block / serial-1024-row form
// (152 us, 5% occupancy) to split-i two-kernel form (2048 blocks each).
// Chunk stats (1 MiB) parked in the S2TCT region (written later in stream).

#define NB 16
#define LC 1024
#define LQ 512
#define DM 512
#define D4 2048
#define NEGINF (-1e30f)
#define BK 32
#define LDAp 40   // padded LDS k-stride (bf16 elems)

typedef __bf16 v8bf __attribute__((ext_vector_type(8)));
typedef __bf16 v4bf __attribute__((ext_vector_type(4)));
typedef float  v4f  __attribute__((ext_vector_type(4)));

#define MFMA16 __builtin_amdgcn_mfma_f32_16x16x32_bf16

#define TILE_SETUP \
  const int t = threadIdx.x, lane = t & 63, wave = t >> 6; \
  const int wm = wave >> 1, wn = wave & 1, quad = lane >> 4, col = lane & 15;

#define ZERO_ACC \
  v4f acc[4][4]; \
  _Pragma("unroll") for (int x = 0; x < 4; ++x) \
  _Pragma("unroll") for (int y = 0; y < 4; ++y) \
  _Pragma("unroll") for (int r = 0; r < 4; ++r) acc[x][y][r] = 0.f;

#define FRAG_MMA(AL, BL) do { \
  v8bf af_[4], bf_[4]; \
  _Pragma("unroll") for (int x = 0; x < 4; ++x) \
    af_[x] = *(const v8bf*)&AL[(wm * 64 + x * 16 + col) * LDAp + quad * 8]; \
  _Pragma("unroll") for (int y = 0; y < 4; ++y) \
    bf_[y] = *(const v8bf*)&BL[(wn * 64 + y * 16 + col) * LDAp + quad * 8]; \
  _Pragma("unroll") for (int x = 0; x < 4; ++x) \
  _Pragma("unroll") for (int y = 0; y < 4; ++y) \
    acc[x][y] = MFMA16(af_[x], bf_[y], acc[x][y], 0, 0, 0); \
} while (0)

// ---------------- K1: cw1[b,i] = C.w1, qw2[b,j] = Q.w2 ----------------
__global__ void k_rowdots(const float* __restrict__ C, const float* __restrict__ Q,
                          const float* __restrict__ w,
                          float* __restrict__ cw1, float* __restrict__ qw2) {
  const int wid = threadIdx.x >> 6, lane = threadIdx.x & 63;
  const int row = blockIdx.x * 4 + wid;
  const bool isC = row < NB * LC;
  const float* src = isC ? (C + (size_t)row * DM) : (Q + (size_t)(row - NB * LC) * DM);
  const float* wv  = isC ? w : (w + DM);
  float v = 0.f;
#pragma unroll
  for (int tt = 0; tt < 8; ++tt) {
    int k = lane + 64 * tt;
    v += src[k] * wv[k];
  }
#pragma unroll
  for (int off = 32; off; off >>= 1) v += __shfl_down(v, off, 64);
  if (lane == 0) {
    if (isC) cw1[row] = v;
    else     qw2[row - NB * LC] = v;
  }
}

// ---------------- G1: S = cw1 + qw2 + (C*w3) @ Q^T ----------------
__global__ __launch_bounds__(256) void k_mfma_S(
    const float* __restrict__ C, const float* __restrict__ Q, const float* __restrict__ w,
    const float* __restrict__ cw1, const float* __restrict__ qw2, float* __restrict__ S) {
  __shared__ __bf16 Al[128 * LDAp], Bl[128 * LDAp];
  const int b = blockIdx.z, i0 = blockIdx.y * 128, j0 = blockIdx.x * 128;
  TILE_SETUP
  const float* Cb = C + (size_t)b * LC * DM;
  const float* Qb = Q + (size_t)b * LQ * DM;
  const float* w3 = w + 2 * DM;
  const int sr = t >> 1, skc = (t & 1) * 16;
  ZERO_ACC
  for (int k0 = 0; k0 < DM; k0 += BK) {
    const float* ca = Cb + (size_t)(i0 + sr) * DM + k0 + skc;
    const float* qa = Qb + (size_t)(j0 + sr) * DM + k0 + skc;
    const float* wa = w3 + k0 + skc;
#pragma unroll
    for (int u = 0; u < 4; ++u) {
      float4 cf = *(const float4*)(ca + 4 * u);
      float4 wf = *(const float4*)(wa + 4 * u);
      float4 qf = *(const float4*)(qa + 4 * u);
      v4bf ah, bh;
      ah[0] = (__bf16)(cf.x * wf.x); ah[1] = (__bf16)(cf.y * wf.y);
      ah[2] = (__bf16)(cf.z * wf.z); ah[3] = (__bf16)(cf.w * wf.w);
      bh[0] = (__bf16)qf.x; bh[1] = (__bf16)qf.y; bh[2] = (__bf16)qf.z; bh[3] = (__bf16)qf.w;
      *(v4bf*)&Al[sr * LDAp + skc + 4 * u] = ah;
      *(v4bf*)&Bl[sr * LDAp + skc + 4 * u] = bh;
    }
    __syncthreads();
    FRAG_MMA(Al, Bl);
    __syncthreads();
  }
  float* Sb = S + (size_t)b * LC * LQ;
#pragma unroll
  for (int x = 0; x < 4; ++x) {
    const int mB = i0 + wm * 64 + x * 16 + quad * 4;
    float cv[4];
#pragma unroll
    for (int r = 0; r < 4; ++r) cv[r] = cw1[b * LC + mB + r];
#pragma unroll
    for (int y = 0; y < 4; ++y) {
      const int j = j0 + wn * 64 + y * 16 + col;
      const float qv = qw2[b * LQ + j];
#pragma unroll
      for (int r = 0; r < 4; ++r)
        Sb[(size_t)(mB + r) * LQ + j] = acc[x][y][r] + cv[r] + qv;
    }
  }
}

// ---------------- row softmax over j (qmask) -> S1 bf16 ----------------
__global__ void k_rowsoftmax(const float* __restrict__ S, const float* __restrict__ qmask,
                             __bf16* __restrict__ S1) {
  const int wid = threadIdx.x >> 6, lane = threadIdx.x & 63;
  const int row = blockIdx.x * 4 + wid;
  const int b = row >> 10;
  const float* Srow = S + (size_t)row * LQ;
  const float* qm = qmask + b * LQ;
  float logit[8];
  float m = -3e38f;
#pragma unroll
  for (int tt = 0; tt < 8; ++tt) {
    int j = lane + 64 * tt;
    float mk = qm[j];
    logit[tt] = mk * Srow[j] + (1.f - mk) * NEGINF;
    m = fmaxf(m, logit[tt]);
  }
#pragma unroll
  for (int off = 32; off; off >>= 1) m = fmaxf(m, __shfl_xor(m, off, 64));
  float e[8];
  float s = 0.f;
#pragma unroll
  for (int tt = 0; tt < 8; ++tt) { e[tt] = __expf(logit[tt] - m); s += e[tt]; }
#pragma unroll
  for (int off = 32; off; off >>= 1) s += __shfl_xor(s, off, 64);
  float inv = 1.f / s;
  __bf16* Orow = S1 + (size_t)row * LQ;
#pragma unroll
  for (int tt = 0; tt < 8; ++tt) Orow[lane + 64 * tt] = (__bf16)(e[tt] * inv);
}

// ------- col softmax phase 1: per-(64i chunk, 64j) online (m,s) stats -------
__global__ void k_colstat(const float* __restrict__ S, const float* __restrict__ cmask,
                          float2* __restrict__ pstat) {
  // grid (LQ/64, LC/64 chunks, NB), block 256
  __shared__ float sm[4][64], ss[4][64];
  const int b = blockIdx.z, ic = blockIdx.y, j0 = blockIdx.x * 64;
  const int c = threadIdx.x & 63, ip = threadIdx.x >> 6;
  const float* Sb = S + ((size_t)b * LC + ic * 64) * LQ;
  const float* cm = cmask + b * LC + ic * 64;
  float m = -3e38f, s = 0.f;
  for (int r = ip; r < 64; r += 4) {
    float mk = cm[r];
    float logit = mk * Sb[(size_t)r * LQ + j0 + c] + (1.f - mk) * NEGINF;
    if (logit > m) { s *= __expf(m - logit); m = logit; }
    s += __expf(logit - m);
  }
  sm[ip][c] = m; ss[ip][c] = s;
  __syncthreads();
  if (ip == 0) {
    float M = m, Sd = s;
#pragma unroll
    for (int r = 1; r < 4; ++r) {
      float mr = sm[r][c], sr = ss[r][c];
      float nM = fmaxf(M, mr);
      Sd = Sd * __expf(M - nM) + sr * __expf(mr - nM);
      M = nM;
    }
    pstat[((size_t)(b * 16 + ic) * LQ) + j0 + c] = make_float2(M, Sd);
  }
}

// ------- col softmax phase 2: combine 16 chunk stats, write S2 bf16 -------
__global__ void k_colwrite(const float* __restrict__ S, const float* __restrict__ cmask,
                           const float2* __restrict__ pstat, __bf16* __restrict__ S2) {
  __shared__ float Mf[64], If[64];
  const int b = blockIdx.z, ic = blockIdx.y, j0 = blockIdx.x * 64;
  const int c = threadIdx.x & 63, ip = threadIdx.x >> 6;
  if (threadIdx.x < 64) {
    float M = -3e38f, Sd = 0.f;
#pragma unroll
    for (int k = 0; k < 16; ++k) {
      float2 p = pstat[((size_t)(b * 16 + k) * LQ) + j0 + threadIdx.x];
      float nM = fmaxf(M, p.x);
      Sd = Sd * __expf(M - nM) + p.y * __expf(p.x - nM);
      M = nM;
    }
    Mf[threadIdx.x] = M; If[threadIdx.x] = 1.f / Sd;
  }
  __syncthreads();
  const float M = Mf[c], inv = If[c];
  const float* Sb = S + ((size_t)b * LC + ic * 64) * LQ;
  const float* cm = cmask + b * LC + ic * 64;
  __bf16* S2b = S2 + ((size_t)b * LC + ic * 64) * LQ;
  for (int r = ip; r < 64; r += 4) {
    float mk = cm[r];
    float logit = mk * Sb[(size_t)r * LQ + j0 + c] + (1.f - mk) * NEGINF;
    S2b[(size_t)r * LQ + j0 + c] = (__bf16)(__expf(logit - M) * inv);
  }
}

// ---------------- G2: A = S1 @ Q ----------------
__global__ __launch_bounds__(256) void k_mfma_A(
    const __bf16* __restrict__ S1, const float* __restrict__ Q, __bf16* __restrict__ Aw) {
  __shared__ __bf16 Al[128 * LDAp], Bl[128 * LDAp];
  const int b = blockIdx.z, i0 = blockIdx.y * 128, n0 = blockIdx.x * 128;
  TILE_SETUP
  const __bf16* S1b = S1 + (size_t)b * LC * LQ;
  const float*  Qb  = Q  + (size_t)b * LQ * DM;
  const int ar = t >> 1, akc = (t & 1) * 16;
  const int kk = t >> 3, nn = (t & 7) * 16;
  ZERO_ACC
  for (int k0 = 0; k0 < LQ; k0 += BK) {
    const __bf16* sa = S1b + (size_t)(i0 + ar) * LQ + k0 + akc;
#pragma unroll
    for (int u = 0; u < 2; ++u)
      *(v8bf*)&Al[ar * LDAp + akc + 8 * u] = *(const v8bf*)(sa + 8 * u);
    const float* qa = Qb + (size_t)(k0 + kk) * DM + n0 + nn;
#pragma unroll
    for (int u = 0; u < 4; ++u) {
      float4 f = *(const float4*)(qa + 4 * u);
      Bl[(nn + 4 * u + 0) * LDAp + kk] = (__bf16)f.x;
      Bl[(nn + 4 * u + 1) * LDAp + kk] = (__bf16)f.y;
      Bl[(nn + 4 * u + 2) * LDAp + kk] = (__bf16)f.z;
      Bl[(nn + 4 * u + 3) * LDAp + kk] = (__bf16)f.w;
    }
    __syncthreads();
    FRAG_MMA(Al, Bl);
    __syncthreads();
  }
  __bf16* Ab = Aw + (size_t)b * LC * DM;
#pragma unroll
  for (int x = 0; x < 4; ++x) {
    const int mB = i0 + wm * 64 + x * 16 + quad * 4;
#pragma unroll
    for (int y = 0; y < 4; ++y) {
      const int n = n0 + wn * 64 + y * 16 + col;
#pragma unroll
      for (int r = 0; r < 4; ++r)
        Ab[(size_t)(mB + r) * DM + n] = (__bf16)acc[x][y][r];
    }
  }
}

// ------- G3: S2TC^T[n][j] = (S2^T @ C)^T ----------
__global__ __launch_bounds__(256) void k_mfma_T(
    const __bf16* __restrict__ S2, const float* __restrict__ C, __bf16* __restrict__ S2TCT) {
  __shared__ __bf16 Al[128 * LDAp], Bl[128 * LDAp];
  const int b = blockIdx.z, j0 = blockIdx.y * 128, n0 = blockIdx.x * 128;
  TILE_SETUP
  const __bf16* S2b = S2 + (size_t)b * LC * LQ;
  const float*  Cb  = C  + (size_t)b * LC * DM;
  const int kk = t >> 3, jj = (t & 7) * 16;
  ZERO_ACC
  for (int k0 = 0; k0 < LC; k0 += BK) {
    const __bf16* sa = S2b + (size_t)(k0 + kk) * LQ + j0 + jj;
    v8bf s0 = *(const v8bf*)(sa), s1 = *(const v8bf*)(sa + 8);
#pragma unroll
    for (int u = 0; u < 8; ++u) {
      Al[(jj + u) * LDAp + kk]     = s0[u];
      Al[(jj + 8 + u) * LDAp + kk] = s1[u];
    }
    const float* cb2 = Cb + (size_t)(k0 + kk) * DM + n0 + jj;
#pragma unroll
    for (int u = 0; u < 4; ++u) {
      float4 f = *(const float4*)(cb2 + 4 * u);
      Bl[(jj + 4 * u + 0) * LDAp + kk] = (__bf16)f.x;
      Bl[(jj + 4 * u + 1) * LDAp + kk] = (__bf16)f.y;
      Bl[(jj + 4 * u + 2) * LDAp + kk] = (__bf16)f.z;
      Bl[(jj + 4 * u + 3) * LDAp + kk] = (__bf16)f.w;
    }
    __syncthreads();
    FRAG_MMA(Al, Bl);
    __syncthreads();
  }
#pragma unroll
  for (int x = 0; x < 4; ++x) {
    const int jB = j0 + wm * 64 + x * 16 + quad * 4;
#pragma unroll
    for (int y = 0; y < 4; ++y) {
      const int n = n0 + wn * 64 + y * 16 + col;
      v4bf h;
#pragma unroll
      for (int r = 0; r < 4; ++r) h[r] = (__bf16)acc[x][y][r];
      *(v4bf*)&S2TCT[((size_t)b * DM + n) * LQ + jB] = h;
    }
  }
}

// ---------------- G4: Bm = S1 @ S2TC ----------------
__global__ __launch_bounds__(256) void k_mfma_Bm(
    const __bf16* __restrict__ S1, const __bf16* __restrict__ S2TCT, __bf16* __restrict__ Bmw) {
  __shared__ __bf16 Al[128 * LDAp], Bl[128 * LDAp];
  const int b = blockIdx.z, i0 = blockIdx.y * 128, n0 = blockIdx.x * 128;
  TILE_SETUP
  const __bf16* S1b = S1 + (size_t)b * LC * LQ;
  const __bf16* Tb  = S2TCT + (size_t)b * DM * LQ;
  const int ar = t >> 1, akc = (t & 1) * 16;
  ZERO_ACC
  for (int k0 = 0; k0 < LQ; k0 += BK) {
    const __bf16* sa = S1b + (size_t)(i0 + ar) * LQ + k0 + akc;
    const __bf16* ta = Tb + (size_t)(n0 + ar) * LQ + k0 + akc;
#pragma unroll
    for (int u = 0; u < 2; ++u) {
      *(v8bf*)&Al[ar * LDAp + akc + 8 * u] = *(const v8bf*)(sa + 8 * u);
      *(v8bf*)&Bl[ar * LDAp + akc + 8 * u] = *(const v8bf*)(ta + 8 * u);
    }
    __syncthreads();
    FRAG_MMA(Al, Bl);
    __syncthreads();
  }
  __bf16* Bb = Bmw + (size_t)b * LC * DM;
#pragma unroll
  for (int x = 0; x < 4; ++x) {
    const int mB = i0 + wm * 64 + x * 16 + quad * 4;
#pragma unroll
    for (int y = 0; y < 4; ++y) {
      const int n = n0 + wn * 64 + y * 16 + col;
#pragma unroll
      for (int r = 0; r < 4; ++r)
        Bb[(size_t)(mB + r) * DM + n] = (__bf16)acc[x][y][r];
    }
  }
}

// -------- G5: out = [C, A, C*A, C*Bm] @ out_w^T + out_b ----------
__global__ __launch_bounds__(256) void k_mfma_out(
    const float* __restrict__ C, const __bf16* __restrict__ Aw, const __bf16* __restrict__ Bmw,
    const float* __restrict__ OW, const float* __restrict__ ob, float* __restrict__ out) {
  __shared__ __bf16 Al[128 * LDAp], Bl[128 * LDAp];
  const int b = blockIdx.z, i0 = blockIdx.y * 128, n0 = blockIdx.x * 128;
  TILE_SETUP
  const float*  Cb  = C   + (size_t)b * LC * DM;
  const __bf16* Ab  = Aw  + (size_t)b * LC * DM;
  const __bf16* Bb  = Bmw + (size_t)b * LC * DM;
  const int ar = t >> 1, akc = (t & 1) * 16;
  ZERO_ACC
  for (int k0 = 0; k0 < D4; k0 += BK) {
    const int seg = k0 >> 9;
    const int kl = (k0 & 511) + akc;
    const float* cr = Cb + (size_t)(i0 + ar) * DM + kl;
    if (seg == 0) {
#pragma unroll
      for (int u = 0; u < 4; ++u) {
        float4 f = *(const float4*)(cr + 4 * u);
        v4bf h; h[0] = (__bf16)f.x; h[1] = (__bf16)f.y; h[2] = (__bf16)f.z; h[3] = (__bf16)f.w;
        *(v4bf*)&Al[ar * LDAp + akc + 4 * u] = h;
      }
    } else if (seg == 1) {
      const __bf16* ap = Ab + (size_t)(i0 + ar) * DM + kl;
#pragma unroll
      for (int u = 0; u < 2; ++u)
        *(v8bf*)&Al[ar * LDAp + akc + 8 * u] = *(const v8bf*)(ap + 8 * u);
    } else if (seg == 2) {
      const __bf16* ap = Ab + (size_t)(i0 + ar) * DM + kl;
#pragma unroll
      for (int u = 0; u < 2; ++u) {
        v8bf av = *(const v8bf*)(ap + 8 * u);
        float4 f0 = *(const float4*)(cr + 8 * u);
        float4 f1 = *(const float4*)(cr + 8 * u + 4);
        v8bf h;
        h[0] = (__bf16)(f0.x * (float)av[0]); h[1] = (__bf16)(f0.y * (float)av[1]);
        h[2] = (__bf16)(f0.z * (float)av[2]); h[3] = (__bf16)(f0.w * (float)av[3]);
        h[4] = (__bf16)(f1.x * (float)av[4]); h[5] = (__bf16)(f1.y * (float)av[5]);
        h[6] = (__bf16)(f1.z * (float)av[6]); h[7] = (__bf16)(f1.w * (float)av[7]);
        *(v8bf*)&Al[ar * LDAp + akc + 8 * u] = h;
      }
    } else {
      const __bf16* bp = Bb + (size_t)(i0 + ar) * DM + kl;
#pragma unroll
      for (int u = 0; u < 2; ++u) {
        v8bf bv = *(const v8bf*)(bp + 8 * u);
        float4 f0 = *(const float4*)(cr + 8 * u);
        float4 f1 = *(const float4*)(cr + 8 * u + 4);
        v8bf h;
        h[0] = (__bf16)(f0.x * (float)bv[0]); h[1] = (__bf16)(f0.y * (float)bv[1]);
        h[2] = (__bf16)(f0.z * (float)bv[2]); h[3] = (__bf16)(f0.w * (float)bv[3]);
        h[4] = (__bf16)(f1.x * (float)bv[4]); h[5] = (__bf16)(f1.y * (float)bv[5]);
        h[6] = (__bf16)(f1.z * (float)bv[6]); h[7] = (__bf16)(f1.w * (float)bv[7]);
        *(v8bf*)&Al[ar * LDAp + akc + 8 * u] = h;
      }
    }
    const float* owr = OW + (size_t)(n0 + ar) * D4 + k0 + akc;
#pragma unroll
    for (int u = 0; u < 4; ++u) {
      float4 f = *(const float4*)(owr + 4 * u);
      v4bf h; h[0] = (__bf16)f.x; h[1] = (__bf16)f.y; h[2] = (__bf16)f.z; h[3] = (__bf16)f.w;
      *(v4bf*)&Bl[ar * LDAp + akc + 4 * u] = h;
    }
    __syncthreads();
    FRAG_MMA(Al, Bl);
    __syncthreads();
  }
  float* outb = out + (size_t)b * LC * DM;
#pragma unroll
  for (int x = 0; x < 4; ++x) {
    const int mB = i0 + wm * 64 + x * 16 + quad * 4;
#pragma unroll
    for (int y = 0; y < 4; ++y) {
      const int n = n0 + wn * 64 + y * 16 + col;
      const float bv = ob[n];
#pragma unroll
      for (int r = 0; r < 4; ++r)
        outb[(size_t)(mB + r) * DM + n] = acc[x][y][r] + bv;
    }
  }
}

extern "C" void kernel_launch(void* const* d_in, const int* in_sizes, int n_in,
                              void* d_out, int out_size, void* d_ws, size_t ws_size,
                              hipStream_t stream) {
  const float* C     = (const float*)d_in[0];
  const float* Q     = (const float*)d_in[1];
  const float* cmask = (const float*)d_in[2];
  const float* qmask = (const float*)d_in[3];
  const float* w     = (const float*)d_in[4];
  const float* out_w = (const float*)d_in[5];
  const float* out_b = (const float*)d_in[6];
  float* out = (float*)d_out;

  // ---- workspace carve (72 MiB + 128 KiB; validated) ----
  char* base = (char*)d_ws;
  float*  cw1   = (float*)base;                                // 64 KiB
  float*  qw2   = (float*)(base + 65536);                      // 32 KiB
  char*   R     = base + 131072;
  float*  S     = (float*)R;                                   // 32 MiB (f32 scores)
  __bf16* Aw    = (__bf16*)R;                                  // alias S[0:16Mi)
  __bf16* Bmw   = (__bf16*)(R + (16u << 20));                  // alias S[16Mi:32Mi)
  __bf16* S1    = (__bf16*)(base + 131072 + (32u << 20));      // 16 MiB
  __bf16* S2    = (__bf16*)(base + 131072 + (48u << 20));      // 16 MiB
  __bf16* S2TCT = (__bf16*)(base + 131072 + (64u << 20));      //  8 MiB
  float2* pstat = (float2*)S2TCT;  // 1 MiB, consumed before k_mfma_T writes here
  (void)in_sizes; (void)n_in; (void)out_size; (void)ws_size;

  k_rowdots<<<(NB * LC + NB * LQ) / 4, 256, 0, stream>>>(C, Q, w, cw1, qw2);
  k_mfma_S<<<dim3(LQ / 128, LC / 128, NB), 256, 0, stream>>>(C, Q, w, cw1, qw2, S);
  k_rowsoftmax<<<NB * LC / 4, 256, 0, stream>>>(S, qmask, S1);
  k_colstat<<<dim3(LQ / 64, LC / 64, NB), 256, 0, stream>>>(S, cmask, pstat);
  k_colwrite<<<dim3(LQ / 64, LC / 64, NB), 256, 0, stream>>>(S, cmask, pstat, S2);
  k_mfma_A<<<dim3(DM / 128, LC / 128, NB), 256, 0, stream>>>(S1, Q, Aw);
  k_mfma_T<<<dim3(DM / 128, LQ / 128, NB), 256, 0, stream>>>(S2, C, S2TCT);
  k_mfma_Bm<<<dim3(DM / 128, LC / 128, NB), 256, 0, stream>>>(S1, S2TCT, Bmw);
  k_mfma_out<<<dim3(DM / 128, LC / 128, NB), 256, 0, stream>>>(C, Aw, Bmw, out_w, out_b, out);
}

// Round 6
// 319.338 us; speedup vs baseline: 5.1660x; 1.2347x over previous
//
#include <hip/hip_runtime.h>
#include <hip/hip_bf16.h>

// CQAttention: B=16, Lc=1024, Lq=512, d=512.  f32 I/O, bf16 MFMA GEMMs, f32 acc.
// Round 6: (1) G5 restructured to read C/A/Bm once per k-chunk and build all 4
// concat-segment tiles in LDS (80 KB, 64 MFMA/barrier) — kills the 3x C re-read;
// (2) XCD-aware block swizzle on all MFMA GEMMs so n-tile siblings sharing an
// A-tile land on the same XCD L2; (3) rowsoftmax+colstat fused (one S read).

#define NB 16
#define LC 1024
#define LQ 512
#define DM 512
#define D4 2048
#define NEGINF (-1e30f)
#define BK 32
#define LDAp 40   // padded LDS k-stride (bf16 elems)

typedef __bf16 v8bf __attribute__((ext_vector_type(8)));
typedef __bf16 v4bf __attribute__((ext_vector_type(4)));
typedef float  v4f  __attribute__((ext_vector_type(4)));

#define MFMA16 __builtin_amdgcn_mfma_f32_16x16x32_bf16

#define TILE_SETUP \
  const int t = threadIdx.x, lane = t & 63, wave = t >> 6; \
  const int wm = wave >> 1, wn = wave & 1, quad = lane >> 4, col = lane & 15;

#define ZERO_ACC \
  v4f acc[4][4]; \
  _Pragma("unroll") for (int x = 0; x < 4; ++x) \
  _Pragma("unroll") for (int y = 0; y < 4; ++y) \
  _Pragma("unroll") for (int r = 0; r < 4; ++r) acc[x][y][r] = 0.f;

#define FRAG_MMA(AL, BL) do { \
  v8bf af_[4], bf_[4]; \
  _Pragma("unroll") for (int x = 0; x < 4; ++x) \
    af_[x] = *(const v8bf*)&AL[(wm * 64 + x * 16 + col) * LDAp + quad * 8]; \
  _Pragma("unroll") for (int y = 0; y < 4; ++y) \
    bf_[y] = *(const v8bf*)&BL[(wn * 64 + y * 16 + col) * LDAp + quad * 8]; \
  _Pragma("unroll") for (int x = 0; x < 4; ++x) \
  _Pragma("unroll") for (int y = 0; y < 4; ++y) \
    acc[x][y] = MFMA16(af_[x], bf_[y], acc[x][y], 0, 0, 0); \
} while (0)

// XCD-aware remap: consecutive blockIdx round-robins XCDs; regroup so works
// 8 apart (same XCD) are consecutive -> n-tile siblings co-resident per XCD L2.
__device__ __forceinline__ void xcd_remap(int& bx, int& by, int& bz) {
  const int gx = gridDim.x, gy = gridDim.y, gz = gridDim.z;
  int flat = bx + gx * (by + gy * bz);
  int per = (gx * gy * gz) >> 3;
  int nw = (flat & 7) * per + (flat >> 3);
  bx = nw % gx;
  int r = nw / gx;
  by = r % gy;
  bz = r / gy;
}

// ---------------- K1: cw1[b,i] = C.w1, qw2[b,j] = Q.w2 ----------------
__global__ void k_rowdots(const float* __restrict__ C, const float* __restrict__ Q,
                          const float* __restrict__ w,
                          float* __restrict__ cw1, float* __restrict__ qw2) {
  const int wid = threadIdx.x >> 6, lane = threadIdx.x & 63;
  const int row = blockIdx.x * 4 + wid;
  const bool isC = row < NB * LC;
  const float* src = isC ? (C + (size_t)row * DM) : (Q + (size_t)(row - NB * LC) * DM);
  const float* wv  = isC ? w : (w + DM);
  float v = 0.f;
#pragma unroll
  for (int tt = 0; tt < 8; ++tt) {
    int k = lane + 64 * tt;
    v += src[k] * wv[k];
  }
#pragma unroll
  for (int off = 32; off; off >>= 1) v += __shfl_down(v, off, 64);
  if (lane == 0) {
    if (isC) cw1[row] = v;
    else     qw2[row - NB * LC] = v;
  }
}

// ---------------- G1: S = cw1 + qw2 + (C*w3) @ Q^T ----------------
__global__ __launch_bounds__(256) void k_mfma_S(
    const float* __restrict__ C, const float* __restrict__ Q, const float* __restrict__ w,
    const float* __restrict__ cw1, const float* __restrict__ qw2, float* __restrict__ S) {
  __shared__ __bf16 Al[128 * LDAp], Bl[128 * LDAp];
  int bx = blockIdx.x, by = blockIdx.y, bz = blockIdx.z;
  xcd_remap(bx, by, bz);
  const int b = bz, i0 = by * 128, j0 = bx * 128;
  TILE_SETUP
  const float* Cb = C + (size_t)b * LC * DM;
  const float* Qb = Q + (size_t)b * LQ * DM;
  const float* w3 = w + 2 * DM;
  const int sr = t >> 1, skc = (t & 1) * 16;
  ZERO_ACC
  for (int k0 = 0; k0 < DM; k0 += BK) {
    const float* ca = Cb + (size_t)(i0 + sr) * DM + k0 + skc;
    const float* qa = Qb + (size_t)(j0 + sr) * DM + k0 + skc;
    const float* wa = w3 + k0 + skc;
#pragma unroll
    for (int u = 0; u < 4; ++u) {
      float4 cf = *(const float4*)(ca + 4 * u);
      float4 wf = *(const float4*)(wa + 4 * u);
      float4 qf = *(const float4*)(qa + 4 * u);
      v4bf ah, bh;
      ah[0] = (__bf16)(cf.x * wf.x); ah[1] = (__bf16)(cf.y * wf.y);
      ah[2] = (__bf16)(cf.z * wf.z); ah[3] = (__bf16)(cf.w * wf.w);
      bh[0] = (__bf16)qf.x; bh[1] = (__bf16)qf.y; bh[2] = (__bf16)qf.z; bh[3] = (__bf16)qf.w;
      *(v4bf*)&Al[sr * LDAp + skc + 4 * u] = ah;
      *(v4bf*)&Bl[sr * LDAp + skc + 4 * u] = bh;
    }
    __syncthreads();
    FRAG_MMA(Al, Bl);
    __syncthreads();
  }
  float* Sb = S + (size_t)b * LC * LQ;
#pragma unroll
  for (int x = 0; x < 4; ++x) {
    const int mB = i0 + wm * 64 + x * 16 + quad * 4;
    float cv[4];
#pragma unroll
    for (int r = 0; r < 4; ++r) cv[r] = cw1[b * LC + mB + r];
#pragma unroll
    for (int y = 0; y < 4; ++y) {
      const int j = j0 + wn * 64 + y * 16 + col;
      const float qv = qw2[b * LQ + j];
#pragma unroll
      for (int r = 0; r < 4; ++r)
        Sb[(size_t)(mB + r) * LQ + j] = acc[x][y][r] + cv[r] + qv;
    }
  }
}

// ---- fused: row softmax (qmask) -> S1  AND  per-64i-chunk column stats ----
__global__ __launch_bounds__(1024) void k_softstat(
    const float* __restrict__ S, const float* __restrict__ qmask,
    const float* __restrict__ cmask, __bf16* __restrict__ S1,
    float2* __restrict__ pstat) {
  __shared__ float2 cst[16][LQ];   // 64 KiB
  const int b = blockIdx.y, ic = blockIdx.x;
  const int tid = threadIdx.x, wv = tid >> 6, lane = tid & 63;
  const float* qm  = qmask + b * LQ;
  const float* cm  = cmask + b * LC + ic * 64;
  const float* Sb  = S  + ((size_t)b * LC + ic * 64) * LQ;
  __bf16*      S1b = S1 + ((size_t)b * LC + ic * 64) * LQ;
  float colm[8], cols[8];
#pragma unroll
  for (int tt = 0; tt < 8; ++tt) { colm[tt] = -3e38f; cols[tt] = 0.f; }
  for (int it = 0; it < 4; ++it) {
    const int r = wv * 4 + it;
    const float cmv = cm[r];
    const float* Srow = Sb + (size_t)r * LQ;
    float sv[8], l1[8];
    float m = -3e38f;
#pragma unroll
    for (int tt = 0; tt < 8; ++tt) {
      int j = lane + 64 * tt;
      sv[tt] = Srow[j];
      float qv = qm[j];
      l1[tt] = qv * sv[tt] + (1.f - qv) * NEGINF;
      m = fmaxf(m, l1[tt]);
    }
#pragma unroll
    for (int off = 32; off; off >>= 1) m = fmaxf(m, __shfl_xor(m, off, 64));
    float e[8], s = 0.f;
#pragma unroll
    for (int tt = 0; tt < 8; ++tt) { e[tt] = __expf(l1[tt] - m); s += e[tt]; }
#pragma unroll
    for (int off = 32; off; off >>= 1) s += __shfl_xor(s, off, 64);
    const float inv = 1.f / s;
#pragma unroll
    for (int tt = 0; tt < 8; ++tt)
      S1b[(size_t)r * LQ + lane + 64 * tt] = (__bf16)(e[tt] * inv);
    // column (S2) stats: mask over i
#pragma unroll
    for (int tt = 0; tt < 8; ++tt) {
      float l2 = cmv * sv[tt] + (1.f - cmv) * NEGINF;
      if (l2 > colm[tt]) { cols[tt] *= __expf(colm[tt] - l2); colm[tt] = l2; }
      cols[tt] += __expf(l2 - colm[tt]);
    }
  }
#pragma unroll
  for (int tt = 0; tt < 8; ++tt) cst[wv][lane + 64 * tt] = make_float2(colm[tt], cols[tt]);
  __syncthreads();
  if (tid < LQ) {
    float M = -3e38f, Sd = 0.f;
#pragma unroll
    for (int k = 0; k < 16; ++k) {
      float2 p = cst[k][tid];
      float nM = fmaxf(M, p.x);
      Sd = Sd * __expf(M - nM) + p.y * __expf(p.x - nM);
      M = nM;
    }
    pstat[((size_t)(b * 16 + ic) * LQ) + tid] = make_float2(M, Sd);
  }
}

// ------- col softmax phase 2: combine 16 chunk stats, write S2 bf16 -------
__global__ void k_colwrite(const float* __restrict__ S, const float* __restrict__ cmask,
                           const float2* __restrict__ pstat, __bf16* __restrict__ S2) {
  __shared__ float Mf[64], If[64];
  const int b = blockIdx.z, ic = blockIdx.y, j0 = blockIdx.x * 64;
  const int c = threadIdx.x & 63, ip = threadIdx.x >> 6;
  if (threadIdx.x < 64) {
    float M = -3e38f, Sd = 0.f;
#pragma unroll
    for (int k = 0; k < 16; ++k) {
      float2 p = pstat[((size_t)(b * 16 + k) * LQ) + j0 + threadIdx.x];
      float nM = fmaxf(M, p.x);
      Sd = Sd * __expf(M - nM) + p.y * __expf(p.x - nM);
      M = nM;
    }
    Mf[threadIdx.x] = M; If[threadIdx.x] = 1.f / Sd;
  }
  __syncthreads();
  const float M = Mf[c], inv = If[c];
  const float* Sb = S + ((size_t)b * LC + ic * 64) * LQ;
  const float* cm = cmask + b * LC + ic * 64;
  __bf16* S2b = S2 + ((size_t)b * LC + ic * 64) * LQ;
  for (int r = ip; r < 64; r += 4) {
    float mk = cm[r];
    float logit = mk * Sb[(size_t)r * LQ + j0 + c] + (1.f - mk) * NEGINF;
    S2b[(size_t)r * LQ + j0 + c] = (__bf16)(__expf(logit - M) * inv);
  }
}

// ---------------- G2: A = S1 @ Q ----------------
__global__ __launch_bounds__(256) void k_mfma_A(
    const __bf16* __restrict__ S1, const float* __restrict__ Q, __bf16* __restrict__ Aw) {
  __shared__ __bf16 Al[128 * LDAp], Bl[128 * LDAp];
  int bx = blockIdx.x, by = blockIdx.y, bz = blockIdx.z;
  xcd_remap(bx, by, bz);
  const int b = bz, i0 = by * 128, n0 = bx * 128;
  TILE_SETUP
  const __bf16* S1b = S1 + (size_t)b * LC * LQ;
  const float*  Qb  = Q  + (size_t)b * LQ * DM;
  const int ar = t >> 1, akc = (t & 1) * 16;
  const int kk = t >> 3, nn = (t & 7) * 16;
  ZERO_ACC
  for (int k0 = 0; k0 < LQ; k0 += BK) {
    const __bf16* sa = S1b + (size_t)(i0 + ar) * LQ + k0 + akc;
#pragma unroll
    for (int u = 0; u < 2; ++u)
      *(v8bf*)&Al[ar * LDAp + akc + 8 * u] = *(const v8bf*)(sa + 8 * u);
    const float* qa = Qb + (size_t)(k0 + kk) * DM + n0 + nn;
#pragma unroll
    for (int u = 0; u < 4; ++u) {
      float4 f = *(const float4*)(qa + 4 * u);
      Bl[(nn + 4 * u + 0) * LDAp + kk] = (__bf16)f.x;
      Bl[(nn + 4 * u + 1) * LDAp + kk] = (__bf16)f.y;
      Bl[(nn + 4 * u + 2) * LDAp + kk] = (__bf16)f.z;
      Bl[(nn + 4 * u + 3) * LDAp + kk] = (__bf16)f.w;
    }
    __syncthreads();
    FRAG_MMA(Al, Bl);
    __syncthreads();
  }
  __bf16* Ab = Aw + (size_t)b * LC * DM;
#pragma unroll
  for (int x = 0; x < 4; ++x) {
    const int mB = i0 + wm * 64 + x * 16 + quad * 4;
#pragma unroll
    for (int y = 0; y < 4; ++y) {
      const int n = n0 + wn * 64 + y * 16 + col;
#pragma unroll
      for (int r = 0; r < 4; ++r)
        Ab[(size_t)(mB + r) * DM + n] = (__bf16)acc[x][y][r];
    }
  }
}

// ------- G3: S2TC^T[n][j] = (S2^T @ C)^T ----------
__global__ __launch_bounds__(256) void k_mfma_T(
    const __bf16* __restrict__ S2, const float* __restrict__ C, __bf16* __restrict__ S2TCT) {
  __shared__ __bf16 Al[128 * LDAp], Bl[128 * LDAp];
  int bx = blockIdx.x, by = blockIdx.y, bz = blockIdx.z;
  xcd_remap(bx, by, bz);
  const int b = bz, j0 = by * 128, n0 = bx * 128;
  TILE_SETUP
  const __bf16* S2b = S2 + (size_t)b * LC * LQ;
  const float*  Cb  = C  + (size_t)b * LC * DM;
  const int kk = t >> 3, jj = (t & 7) * 16;
  ZERO_ACC
  for (int k0 = 0; k0 < LC; k0 += BK) {
    const __bf16* sa = S2b + (size_t)(k0 + kk) * LQ + j0 + jj;
    v8bf s0 = *(const v8bf*)(sa), s1 = *(const v8bf*)(sa + 8);
#pragma unroll
    for (int u = 0; u < 8; ++u) {
      Al[(jj + u) * LDAp + kk]     = s0[u];
      Al[(jj + 8 + u) * LDAp + kk] = s1[u];
    }
    const float* cb2 = Cb + (size_t)(k0 + kk) * DM + n0 + jj;
#pragma unroll
    for (int u = 0; u < 4; ++u) {
      float4 f = *(const float4*)(cb2 + 4 * u);
      Bl[(jj + 4 * u + 0) * LDAp + kk] = (__bf16)f.x;
      Bl[(jj + 4 * u + 1) * LDAp + kk] = (__bf16)f.y;
      Bl[(jj + 4 * u + 2) * LDAp + kk] = (__bf16)f.z;
      Bl[(jj + 4 * u + 3) * LDAp + kk] = (__bf16)f.w;
    }
    __syncthreads();
    FRAG_MMA(Al, Bl);
    __syncthreads();
  }
#pragma unroll
  for (int x = 0; x < 4; ++x) {
    const int jB = j0 + wm * 64 + x * 16 + quad * 4;
#pragma unroll
    for (int y = 0; y < 4; ++y) {
      const int n = n0 + wn * 64 + y * 16 + col;
      v4bf h;
#pragma unroll
      for (int r = 0; r < 4; ++r) h[r] = (__bf16)acc[x][y][r];
      *(v4bf*)&S2TCT[((size_t)b * DM + n) * LQ + jB] = h;
    }
  }
}

// ---------------- G4: Bm = S1 @ S2TC ----------------
__global__ __launch_bounds__(256) void k_mfma_Bm(
    const __bf16* __restrict__ S1, const __bf16* __restrict__ S2TCT, __bf16* __restrict__ Bmw) {
  __shared__ __bf16 Al[128 * LDAp], Bl[128 * LDAp];
  int bx = blockIdx.x, by = blockIdx.y, bz = blockIdx.z;
  xcd_remap(bx, by, bz);
  const int b = bz, i0 = by * 128, n0 = bx * 128;
  TILE_SETUP
  const __bf16* S1b = S1 + (size_t)b * LC * LQ;
  const __bf16* Tb  = S2TCT + (size_t)b * DM * LQ;
  const int ar = t >> 1, akc = (t & 1) * 16;
  ZERO_ACC
  for (int k0 = 0; k0 < LQ; k0 += BK) {
    const __bf16* sa = S1b + (size_t)(i0 + ar) * LQ + k0 + akc;
    const __bf16* ta = Tb + (size_t)(n0 + ar) * LQ + k0 + akc;
#pragma unroll
    for (int u = 0; u < 2; ++u) {
      *(v8bf*)&Al[ar * LDAp + akc + 8 * u] = *(const v8bf*)(sa + 8 * u);
      *(v8bf*)&Bl[ar * LDAp + akc + 8 * u] = *(const v8bf*)(ta + 8 * u);
    }
    __syncthreads();
    FRAG_MMA(Al, Bl);
    __syncthreads();
  }
  __bf16* Bb = Bmw + (size_t)b * LC * DM;
#pragma unroll
  for (int x = 0; x < 4; ++x) {
    const int mB = i0 + wm * 64 + x * 16 + quad * 4;
#pragma unroll
    for (int y = 0; y < 4; ++y) {
      const int n = n0 + wn * 64 + y * 16 + col;
#pragma unroll
      for (int r = 0; r < 4; ++r)
        Bb[(size_t)(mB + r) * DM + n] = (__bf16)acc[x][y][r];
    }
  }
}

// -------- G5: out = [C, A, C*A, C*Bm] @ out_w^T + out_b  (single-read A-side) --
__global__ __launch_bounds__(256) void k_mfma_out(
    const float* __restrict__ C, const __bf16* __restrict__ Aw, const __bf16* __restrict__ Bmw,
    const float* __restrict__ OW, const float* __restrict__ ob, float* __restrict__ out) {
  __shared__ __bf16 Asg[4][128 * LDAp], Bsg[4][128 * LDAp];   // 80 KiB
  int bx = blockIdx.x, by = blockIdx.y, bz = blockIdx.z;
  xcd_remap(bx, by, bz);
  const int b = bz, i0 = by * 128, n0 = bx * 128;
  TILE_SETUP
  const float*  Cb = C   + (size_t)b * LC * DM;
  const __bf16* Ab = Aw  + (size_t)b * LC * DM;
  const __bf16* Bb = Bmw + (size_t)b * LC * DM;
  const int sr = t >> 1, skc = (t & 1) * 16;
  ZERO_ACC
  for (int kl0 = 0; kl0 < DM; kl0 += BK) {
    const float*  cr = Cb + (size_t)(i0 + sr) * DM + kl0 + skc;
    const __bf16* ap = Ab + (size_t)(i0 + sr) * DM + kl0 + skc;
    const __bf16* bp = Bb + (size_t)(i0 + sr) * DM + kl0 + skc;
    // read C (f32 x16), A (bf16 x16), Bm (bf16 x16) ONCE; build 4 segment tiles
#pragma unroll
    for (int u = 0; u < 2; ++u) {
      float4 f0 = *(const float4*)(cr + 8 * u);
      float4 f1 = *(const float4*)(cr + 8 * u + 4);
      v8bf av = *(const v8bf*)(ap + 8 * u);
      v8bf bv = *(const v8bf*)(bp + 8 * u);
      float cf[8] = {f0.x, f0.y, f0.z, f0.w, f1.x, f1.y, f1.z, f1.w};
      v8bf hC, hCA, hCB;
#pragma unroll
      for (int e = 0; e < 8; ++e) {
        hC[e]  = (__bf16)cf[e];
        hCA[e] = (__bf16)(cf[e] * (float)av[e]);
        hCB[e] = (__bf16)(cf[e] * (float)bv[e]);
      }
      const int off = sr * LDAp + skc + 8 * u;
      *(v8bf*)&Asg[0][off] = hC;
      *(v8bf*)&Asg[1][off] = av;
      *(v8bf*)&Asg[2][off] = hCA;
      *(v8bf*)&Asg[3][off] = hCB;
    }
    // B: out_w rows (n) at the 4 segment k-offsets
    const float* owr = OW + (size_t)(n0 + sr) * D4 + kl0 + skc;
#pragma unroll
    for (int s = 0; s < 4; ++s) {
#pragma unroll
      for (int u = 0; u < 4; ++u) {
        float4 f = *(const float4*)(owr + s * DM + 4 * u);
        v4bf h; h[0] = (__bf16)f.x; h[1] = (__bf16)f.y; h[2] = (__bf16)f.z; h[3] = (__bf16)f.w;
        *(v4bf*)&Bsg[s][sr * LDAp + skc + 4 * u] = h;
      }
    }
    __syncthreads();
#pragma unroll
    for (int s = 0; s < 4; ++s) FRAG_MMA(Asg[s], Bsg[s]);
    __syncthreads();
  }
  float* outb = out + (size_t)b * LC * DM;
#pragma unroll
  for (int x = 0; x < 4; ++x) {
    const int mB = i0 + wm * 64 + x * 16 + quad * 4;
#pragma unroll
    for (int y = 0; y < 4; ++y) {
      const int n = n0 + wn * 64 + y * 16 + col;
      const float bv = ob[n];
#pragma unroll
      for (int r = 0; r < 4; ++r)
        outb[(size_t)(mB + r) * DM + n] = acc[x][y][r] + bv;
    }
  }
}

extern "C" void kernel_launch(void* const* d_in, const int* in_sizes, int n_in,
                              void* d_out, int out_size, void* d_ws, size_t ws_size,
                              hipStream_t stream) {
  const float* C     = (const float*)d_in[0];
  const float* Q     = (const float*)d_in[1];
  const float* cmask = (const float*)d_in[2];
  const float* qmask = (const float*)d_in[3];
  const float* w     = (const float*)d_in[4];
  const float* out_w = (const float*)d_in[5];
  const float* out_b = (const float*)d_in[6];
  float* out = (float*)d_out;

  // ---- workspace carve (72 MiB + 128 KiB; validated) ----
  char* base = (char*)d_ws;
  float*  cw1   = (float*)base;                                // 64 KiB
  float*  qw2   = (float*)(base + 65536);                      // 32 KiB
  char*   R     = base + 131072;
  float*  S     = (float*)R;                                   // 32 MiB (f32 scores)
  __bf16* Aw    = (__bf16*)R;                                  // alias S[0:16Mi)
  __bf16* Bmw   = (__bf16*)(R + (16u << 20));                  // alias S[16Mi:32Mi)
  __bf16* S1    = (__bf16*)(base + 131072 + (32u << 20));      // 16 MiB
  __bf16* S2    = (__bf16*)(base + 131072 + (48u << 20));      // 16 MiB
  __bf16* S2TCT = (__bf16*)(base + 131072 + (64u << 20));      //  8 MiB
  float2* pstat = (float2*)S2TCT;  // 1 MiB, consumed before k_mfma_T writes here
  (void)in_sizes; (void)n_in; (void)out_size; (void)ws_size;

  k_rowdots<<<(NB * LC + NB * LQ) / 4, 256, 0, stream>>>(C, Q, w, cw1, qw2);
  k_mfma_S<<<dim3(LQ / 128, LC / 128, NB), 256, 0, stream>>>(C, Q, w, cw1, qw2, S);
  k_softstat<<<dim3(LC / 64, NB), 1024, 0, stream>>>(S, qmask, cmask, S1, pstat);
  k_colwrite<<<dim3(LQ / 64, LC / 64, NB), 256, 0, stream>>>(S, cmask, pstat, S2);
  k_mfma_A<<<dim3(DM / 128, LC / 128, NB), 256, 0, stream>>>(S1, Q, Aw);
  k_mfma_T<<<dim3(DM / 128, LQ / 128, NB), 256, 0, stream>>>(S2, C, S2TCT);
  k_mfma_Bm<<<dim3(DM / 128, LC / 128, NB), 256, 0, stream>>>(S1, S2TCT, Bmw);
  k_mfma_out<<<dim3(DM / 128, LC / 128, NB), 256, 0, stream>>>(C, Aw, Bmw, out_w, out_b, out);
}

// Round 7
// 299.057 us; speedup vs baseline: 5.5164x; 1.0678x over previous
//
#include <hip/hip_runtime.h>
#include <hip/hip_bf16.h>

// CQAttention: B=16, Lc=1024, Lq=512, d=512.  f32 I/O, bf16 MFMA GEMMs, f32 acc.
// Round 7: (1) all MFMA GEMMs -> 512-thread / 8-wave blocks (64x32 wave tile);
// grid was the occupancy cap (2 blocks/CU x 4 waves = 8 waves/CU -> now 16).
// (2) G5 2-segment passes: LDS 80->40 KB. (3) QT/CT materialized + colwrite
// emits S2T: all GEMM staging is v8bf row loads, no scalar LDS transpose writes.

#define NB 16
#define LC 1024
#define LQ 512
#define DM 512
#define D4 2048
#define NEGINF (-1e30f)
#define BK 32
#define LDAp 40   // padded LDS k-stride (bf16): 20-dword row stride -> even bank spread

typedef __bf16 v8bf __attribute__((ext_vector_type(8)));
typedef __bf16 v4bf __attribute__((ext_vector_type(4)));
typedef float  v4f  __attribute__((ext_vector_type(4)));

#define MFMA16 __builtin_amdgcn_mfma_f32_16x16x32_bf16

// 8-wave tile setup: wave (wm in 0..1, wn in 0..3) owns a 64(m) x 32(n) region.
#define TILE_SETUP8 \
  const int t = threadIdx.x, lane = t & 63, wave = t >> 6; \
  const int wm = wave >> 2, wn = wave & 3, quad = lane >> 4, col = lane & 15; \
  const int sr = t >> 2, skc = (t & 3) * 8;

#define ZERO_ACC8 \
  v4f acc[4][2]; \
  _Pragma("unroll") for (int x = 0; x < 4; ++x) \
  _Pragma("unroll") for (int y = 0; y < 2; ++y) \
  _Pragma("unroll") for (int r = 0; r < 4; ++r) acc[x][y][r] = 0.f;

#define FRAG_MMA8(AL, BL) do { \
  v8bf af_[4], bf_[2]; \
  _Pragma("unroll") for (int x = 0; x < 4; ++x) \
    af_[x] = *(const v8bf*)&AL[(wm * 64 + x * 16 + col) * LDAp + quad * 8]; \
  _Pragma("unroll") for (int y = 0; y < 2; ++y) \
    bf_[y] = *(const v8bf*)&BL[(wn * 32 + y * 16 + col) * LDAp + quad * 8]; \
  _Pragma("unroll") for (int x = 0; x < 4; ++x) \
  _Pragma("unroll") for (int y = 0; y < 2; ++y) \
    acc[x][y] = MFMA16(af_[x], bf_[y], acc[x][y], 0, 0, 0); \
} while (0)

// XCD-aware remap (L2 locality for n-tile siblings sharing an A-tile).
__device__ __forceinline__ void xcd_remap(int& bx, int& by, int& bz) {
  const int gx = gridDim.x, gy = gridDim.y, gz = gridDim.z;
  int flat = bx + gx * (by + gy * bz);
  int per = (gx * gy * gz) >> 3;
  int nw = (flat & 7) * per + (flat >> 3);
  bx = nw % gx;
  int r = nw / gx;
  by = r % gy;
  bz = r / gy;
}

__device__ __forceinline__ v8bf cvt8(const float* p) {
  float4 f0 = *(const float4*)p, f1 = *(const float4*)(p + 4);
  v8bf h;
  h[0] = (__bf16)f0.x; h[1] = (__bf16)f0.y; h[2] = (__bf16)f0.z; h[3] = (__bf16)f0.w;
  h[4] = (__bf16)f1.x; h[5] = (__bf16)f1.y; h[6] = (__bf16)f1.z; h[7] = (__bf16)f1.w;
  return h;
}

// ---------------- K1: cw1[b,i] = C.w1, qw2[b,j] = Q.w2 ----------------
__global__ void k_rowdots(const float* __restrict__ C, const float* __restrict__ Q,
                          const float* __restrict__ w,
                          float* __restrict__ cw1, float* __restrict__ qw2) {
  const int wid = threadIdx.x >> 6, lane = threadIdx.x & 63;
  const int row = blockIdx.x * 4 + wid;
  const bool isC = row < NB * LC;
  const float* src = isC ? (C + (size_t)row * DM) : (Q + (size_t)(row - NB * LC) * DM);
  const float* wv  = isC ? w : (w + DM);
  float v = 0.f;
#pragma unroll
  for (int tt = 0; tt < 8; ++tt) {
    int k = lane + 64 * tt;
    v += src[k] * wv[k];
  }
#pragma unroll
  for (int off = 32; off; off >>= 1) v += __shfl_down(v, off, 64);
  if (lane == 0) {
    if (isC) cw1[row] = v;
    else     qw2[row - NB * LC] = v;
  }
}

// ------- batched transpose: f32 in[R][Cd] -> bf16 outT[Cd][R] -------
__global__ void k_transpose(const float* __restrict__ in, __bf16* __restrict__ outT,
                            int R, int Cd) {
  __shared__ __bf16 tile[64][66];
  const int b = blockIdx.z;
  const int r0 = blockIdx.y * 64, c0 = blockIdx.x * 64;
  const int tr = threadIdx.x >> 6, tc = threadIdx.x & 63;
  const float* inb = in + (size_t)b * R * Cd;
  __bf16* outb = outT + (size_t)b * Cd * R;
  for (int r = tr; r < 64; r += 4)
    tile[r][tc] = (__bf16)inb[(size_t)(r0 + r) * Cd + c0 + tc];
  __syncthreads();
  for (int c = tr; c < 64; c += 4)
    outb[(size_t)(c0 + c) * R + r0 + tc] = tile[tc][c];
}

// ---------------- G1: S = cw1 + qw2 + (C*w3) @ Q^T ----------------
__global__ __launch_bounds__(512) void k_mfma_S(
    const float* __restrict__ C, const float* __restrict__ Q, const float* __restrict__ w,
    const float* __restrict__ cw1, const float* __restrict__ qw2, float* __restrict__ S) {
  __shared__ __bf16 Al[128 * LDAp], Bl[128 * LDAp];
  int bx = blockIdx.x, by = blockIdx.y, bz = blockIdx.z;
  xcd_remap(bx, by, bz);
  const int b = bz, i0 = by * 128, j0 = bx * 128;
  TILE_SETUP8
  const float* Cb = C + (size_t)b * LC * DM;
  const float* Qb = Q + (size_t)b * LQ * DM;
  const float* w3 = w + 2 * DM;
  ZERO_ACC8
  for (int k0 = 0; k0 < DM; k0 += BK) {
    const float* ca = Cb + (size_t)(i0 + sr) * DM + k0 + skc;
    const float* qa = Qb + (size_t)(j0 + sr) * DM + k0 + skc;
    const float* wa = w3 + k0 + skc;
    float4 c0 = *(const float4*)ca, c1 = *(const float4*)(ca + 4);
    float4 w0 = *(const float4*)wa, w1 = *(const float4*)(wa + 4);
    v8bf ah;
    ah[0] = (__bf16)(c0.x * w0.x); ah[1] = (__bf16)(c0.y * w0.y);
    ah[2] = (__bf16)(c0.z * w0.z); ah[3] = (__bf16)(c0.w * w0.w);
    ah[4] = (__bf16)(c1.x * w1.x); ah[5] = (__bf16)(c1.y * w1.y);
    ah[6] = (__bf16)(c1.z * w1.z); ah[7] = (__bf16)(c1.w * w1.w);
    *(v8bf*)&Al[sr * LDAp + skc] = ah;
    *(v8bf*)&Bl[sr * LDAp + skc] = cvt8(qa);
    __syncthreads();
    FRAG_MMA8(Al, Bl);
    __syncthreads();
  }
  float* Sb = S + (size_t)b * LC * LQ;
#pragma unroll
  for (int x = 0; x < 4; ++x) {
    const int mB = i0 + wm * 64 + x * 16 + quad * 4;
    float cv[4];
#pragma unroll
    for (int r = 0; r < 4; ++r) cv[r] = cw1[b * LC + mB + r];
#pragma unroll
    for (int y = 0; y < 2; ++y) {
      const int j = j0 + wn * 32 + y * 16 + col;
      const float qv = qw2[b * LQ + j];
#pragma unroll
      for (int r = 0; r < 4; ++r)
        Sb[(size_t)(mB + r) * LQ + j] = acc[x][y][r] + cv[r] + qv;
    }
  }
}

// ---- fused: row softmax (qmask) -> S1  AND  per-64i-chunk column stats ----
__global__ __launch_bounds__(1024) void k_softstat(
    const float* __restrict__ S, const float* __restrict__ qmask,
    const float* __restrict__ cmask, __bf16* __restrict__ S1,
    float2* __restrict__ pstat) {
  __shared__ float2 cst[16][LQ];   // 64 KiB
  const int b = blockIdx.y, ic = blockIdx.x;
  const int tid = threadIdx.x, wv = tid >> 6, lane = tid & 63;
  const float* qm  = qmask + b * LQ;
  const float* cm  = cmask + b * LC + ic * 64;
  const float* Sb  = S  + ((size_t)b * LC + ic * 64) * LQ;
  __bf16*      S1b = S1 + ((size_t)b * LC + ic * 64) * LQ;
  float colm[8], cols[8];
#pragma unroll
  for (int tt = 0; tt < 8; ++tt) { colm[tt] = -3e38f; cols[tt] = 0.f; }
  for (int it = 0; it < 4; ++it) {
    const int r = wv * 4 + it;
    const float cmv = cm[r];
    const float* Srow = Sb + (size_t)r * LQ;
    float sv[8], l1[8];
    float m = -3e38f;
#pragma unroll
    for (int tt = 0; tt < 8; ++tt) {
      int j = lane + 64 * tt;
      sv[tt] = Srow[j];
      float qv = qm[j];
      l1[tt] = qv * sv[tt] + (1.f - qv) * NEGINF;
      m = fmaxf(m, l1[tt]);
    }
#pragma unroll
    for (int off = 32; off; off >>= 1) m = fmaxf(m, __shfl_xor(m, off, 64));
    float e[8], s = 0.f;
#pragma unroll
    for (int tt = 0; tt < 8; ++tt) { e[tt] = __expf(l1[tt] - m); s += e[tt]; }
#pragma unroll
    for (int off = 32; off; off >>= 1) s += __shfl_xor(s, off, 64);
    const float inv = 1.f / s;
#pragma unroll
    for (int tt = 0; tt < 8; ++tt)
      S1b[(size_t)r * LQ + lane + 64 * tt] = (__bf16)(e[tt] * inv);
#pragma unroll
    for (int tt = 0; tt < 8; ++tt) {
      float l2 = cmv * sv[tt] + (1.f - cmv) * NEGINF;
      if (l2 > colm[tt]) { cols[tt] *= __expf(colm[tt] - l2); colm[tt] = l2; }
      cols[tt] += __expf(l2 - colm[tt]);
    }
  }
#pragma unroll
  for (int tt = 0; tt < 8; ++tt) cst[wv][lane + 64 * tt] = make_float2(colm[tt], cols[tt]);
  __syncthreads();
  if (tid < LQ) {
    float M = -3e38f, Sd = 0.f;
#pragma unroll
    for (int k = 0; k < 16; ++k) {
      float2 p = cst[k][tid];
      float nM = fmaxf(M, p.x);
      Sd = Sd * __expf(M - nM) + p.y * __expf(p.x - nM);
      M = nM;
    }
    pstat[((size_t)(b * 16 + ic) * LQ) + tid] = make_float2(M, Sd);
  }
}

// ---- col softmax phase 2: combine chunk stats, write TRANSPOSED S2T[j][i] ----
__global__ void k_colwrite(const float* __restrict__ S, const float* __restrict__ cmask,
                           const float2* __restrict__ pstat, __bf16* __restrict__ S2T) {
  __shared__ float Mf[64], If[64];
  __shared__ __bf16 tile[64][66];
  const int b = blockIdx.z, ic = blockIdx.y, j0 = blockIdx.x * 64;
  const int c = threadIdx.x & 63, ip = threadIdx.x >> 6;
  if (threadIdx.x < 64) {
    float M = -3e38f, Sd = 0.f;
#pragma unroll
    for (int k = 0; k < 16; ++k) {
      float2 p = pstat[((size_t)(b * 16 + k) * LQ) + j0 + threadIdx.x];
      float nM = fmaxf(M, p.x);
      Sd = Sd * __expf(M - nM) + p.y * __expf(p.x - nM);
      M = nM;
    }
    Mf[threadIdx.x] = M; If[threadIdx.x] = 1.f / Sd;
  }
  __syncthreads();
  const float M = Mf[c], inv = If[c];
  const float* Sb = S + ((size_t)b * LC + ic * 64) * LQ;
  const float* cm = cmask + b * LC + ic * 64;
  for (int r = ip; r < 64; r += 4) {
    float mk = cm[r];
    float logit = mk * Sb[(size_t)r * LQ + j0 + c] + (1.f - mk) * NEGINF;
    tile[r][c] = (__bf16)(__expf(logit - M) * inv);   // tile[i_local][j_local]
  }
  __syncthreads();
  __bf16* S2Tb = S2T + ((size_t)b * LQ + j0) * LC + ic * 64;
  for (int jr = ip; jr < 64; jr += 4)
    S2Tb[(size_t)jr * LC + c] = tile[c][jr];
}

// ---------------- G2: A = S1 @ Q  (B-op = QT rows, k=j contiguous) ----------
__global__ __launch_bounds__(512) void k_mfma_A(
    const __bf16* __restrict__ S1, const __bf16* __restrict__ QT, __bf16* __restrict__ Aw) {
  __shared__ __bf16 Al[128 * LDAp], Bl[128 * LDAp];
  int bx = blockIdx.x, by = blockIdx.y, bz = blockIdx.z;
  xcd_remap(bx, by, bz);
  const int b = bz, i0 = by * 128, n0 = bx * 128;
  TILE_SETUP8
  const __bf16* S1b = S1 + (size_t)b * LC * LQ;
  const __bf16* QTb = QT + (size_t)b * DM * LQ;
  ZERO_ACC8
  for (int k0 = 0; k0 < LQ; k0 += BK) {
    *(v8bf*)&Al[sr * LDAp + skc] = *(const v8bf*)(S1b + (size_t)(i0 + sr) * LQ + k0 + skc);
    *(v8bf*)&Bl[sr * LDAp + skc] = *(const v8bf*)(QTb + (size_t)(n0 + sr) * LQ + k0 + skc);
    __syncthreads();
    FRAG_MMA8(Al, Bl);
    __syncthreads();
  }
  __bf16* Ab = Aw + (size_t)b * LC * DM;
#pragma unroll
  for (int x = 0; x < 4; ++x) {
    const int mB = i0 + wm * 64 + x * 16 + quad * 4;
#pragma unroll
    for (int y = 0; y < 2; ++y) {
      const int n = n0 + wn * 32 + y * 16 + col;
#pragma unroll
      for (int r = 0; r < 4; ++r)
        Ab[(size_t)(mB + r) * DM + n] = (__bf16)acc[x][y][r];
    }
  }
}

// ------- G3: S2TC^T[n][j]  (A-op = S2T rows, B-op = CT rows; K=Lc) ----------
__global__ __launch_bounds__(512) void k_mfma_T(
    const __bf16* __restrict__ S2T, const __bf16* __restrict__ CT, __bf16* __restrict__ S2TCT) {
  __shared__ __bf16 Al[128 * LDAp], Bl[128 * LDAp];
  int bx = blockIdx.x, by = blockIdx.y, bz = blockIdx.z;
  xcd_remap(bx, by, bz);
  const int b = bz, j0 = by * 128, n0 = bx * 128;
  TILE_SETUP8
  const __bf16* S2Tb = S2T + (size_t)b * LQ * LC;
  const __bf16* CTb  = CT  + (size_t)b * DM * LC;
  ZERO_ACC8
  for (int k0 = 0; k0 < LC; k0 += BK) {
    *(v8bf*)&Al[sr * LDAp + skc] = *(const v8bf*)(S2Tb + (size_t)(j0 + sr) * LC + k0 + skc);
    *(v8bf*)&Bl[sr * LDAp + skc] = *(const v8bf*)(CTb  + (size_t)(n0 + sr) * LC + k0 + skc);
    __syncthreads();
    FRAG_MMA8(Al, Bl);
    __syncthreads();
  }
#pragma unroll
  for (int x = 0; x < 4; ++x) {
    const int jB = j0 + wm * 64 + x * 16 + quad * 4;
#pragma unroll
    for (int y = 0; y < 2; ++y) {
      const int n = n0 + wn * 32 + y * 16 + col;
      v4bf h;
#pragma unroll
      for (int r = 0; r < 4; ++r) h[r] = (__bf16)acc[x][y][r];
      *(v4bf*)&S2TCT[((size_t)b * DM + n) * LQ + jB] = h;
    }
  }
}

// ---------------- G4: Bm = S1 @ S2TC  (B-op = S2TCT rows) ----------------
__global__ __launch_bounds__(512) void k_mfma_Bm(
    const __bf16* __restrict__ S1, const __bf16* __restrict__ S2TCT, __bf16* __restrict__ Bmw) {
  __shared__ __bf16 Al[128 * LDAp], Bl[128 * LDAp];
  int bx = blockIdx.x, by = blockIdx.y, bz = blockIdx.z;
  xcd_remap(bx, by, bz);
  const int b = bz, i0 = by * 128, n0 = bx * 128;
  TILE_SETUP8
  const __bf16* S1b = S1 + (size_t)b * LC * LQ;
  const __bf16* Tb  = S2TCT + (size_t)b * DM * LQ;
  ZERO_ACC8
  for (int k0 = 0; k0 < LQ; k0 += BK) {
    *(v8bf*)&Al[sr * LDAp + skc] = *(const v8bf*)(S1b + (size_t)(i0 + sr) * LQ + k0 + skc);
    *(v8bf*)&Bl[sr * LDAp + skc] = *(const v8bf*)(Tb  + (size_t)(n0 + sr) * LQ + k0 + skc);
    __syncthreads();
    FRAG_MMA8(Al, Bl);
    __syncthreads();
  }
  __bf16* Bb = Bmw + (size_t)b * LC * DM;
#pragma unroll
  for (int x = 0; x < 4; ++x) {
    const int mB = i0 + wm * 64 + x * 16 + quad * 4;
#pragma unroll
    for (int y = 0; y < 2; ++y) {
      const int n = n0 + wn * 32 + y * 16 + col;
#pragma unroll
      for (int r = 0; r < 4; ++r)
        Bb[(size_t)(mB + r) * DM + n] = (__bf16)acc[x][y][r];
    }
  }
}

// -------- G5: out = [C, A, C*A, C*Bm] @ out_w^T + out_b  (2-seg passes) ------
__global__ __launch_bounds__(512) void k_mfma_out(
    const float* __restrict__ C, const __bf16* __restrict__ Aw, const __bf16* __restrict__ Bmw,
    const float* __restrict__ OW, const float* __restrict__ ob, float* __restrict__ out) {
  __shared__ __bf16 Asg[2][128 * LDAp], Bsg[2][128 * LDAp];   // 40 KiB
  int bx = blockIdx.x, by = blockIdx.y, bz = blockIdx.z;
  xcd_remap(bx, by, bz);
  const int b = bz, i0 = by * 128, n0 = bx * 128;
  TILE_SETUP8
  const float*  Cb = C   + (size_t)b * LC * DM;
  const __bf16* Ab = Aw  + (size_t)b * LC * DM;
  const __bf16* Bb = Bmw + (size_t)b * LC * DM;
  ZERO_ACC8
#pragma unroll
  for (int pass = 0; pass < 2; ++pass) {
    for (int kl0 = 0; kl0 < DM; kl0 += BK) {
      const float*  cr = Cb + (size_t)(i0 + sr) * DM + kl0 + skc;
      const __bf16* ap = Ab + (size_t)(i0 + sr) * DM + kl0 + skc;
      const int off = sr * LDAp + skc;
      v8bf av = *(const v8bf*)ap;
      if (pass == 0) {                       // segs 0 (C), 1 (A)
        *(v8bf*)&Asg[0][off] = cvt8(cr);
        *(v8bf*)&Asg[1][off] = av;
      } else {                               // segs 2 (C*A), 3 (C*Bm)
        float4 f0 = *(const float4*)cr, f1 = *(const float4*)(cr + 4);
        v8bf bv = *(const v8bf*)(Bb + (size_t)(i0 + sr) * DM + kl0 + skc);
        float cf[8] = {f0.x, f0.y, f0.z, f0.w, f1.x, f1.y, f1.z, f1.w};
        v8bf hCA, hCB;
#pragma unroll
        for (int e = 0; e < 8; ++e) {
          hCA[e] = (__bf16)(cf[e] * (float)av[e]);
          hCB[e] = (__bf16)(cf[e] * (float)bv[e]);
        }
        *(v8bf*)&Asg[0][off] = hCA;
        *(v8bf*)&Asg[1][off] = hCB;
      }
      const float* owr = OW + (size_t)(n0 + sr) * D4 + pass * 2 * DM + kl0 + skc;
      *(v8bf*)&Bsg[0][off] = cvt8(owr);
      *(v8bf*)&Bsg[1][off] = cvt8(owr + DM);
      __syncthreads();
      FRAG_MMA8(Asg[0], Bsg[0]);
      FRAG_MMA8(Asg[1], Bsg[1]);
      __syncthreads();
    }
  }
  float* outb = out + (size_t)b * LC * DM;
#pragma unroll
  for (int x = 0; x < 4; ++x) {
    const int mB = i0 + wm * 64 + x * 16 + quad * 4;
#pragma unroll
    for (int y = 0; y < 2; ++y) {
      const int n = n0 + wn * 32 + y * 16 + col;
      const float bv = ob[n];
#pragma unroll
      for (int r = 0; r < 4; ++r)
        outb[(size_t)(mB + r) * DM + n] = acc[x][y][r] + bv;
    }
  }
}

extern "C" void kernel_launch(void* const* d_in, const int* in_sizes, int n_in,
                              void* d_out, int out_size, void* d_ws, size_t ws_size,
                              hipStream_t stream) {
  const float* C     = (const float*)d_in[0];
  const float* Q     = (const float*)d_in[1];
  const float* cmask = (const float*)d_in[2];
  const float* qmask = (const float*)d_in[3];
  const float* w     = (const float*)d_in[4];
  const float* out_w = (const float*)d_in[5];
  const float* out_b = (const float*)d_in[6];
  float* out = (float*)d_out;

  // ---- workspace carve (72 MiB + 128 KiB; validated). Aliased by lifetime:
  //  R[0,16Mi):   S.lo            -> Aw            (S dead after colwrite)
  //  R[16,32Mi):  S.hi            -> CT -> Bmw     (CT dead after k_mfma_T)
  //  +32Mi:       S1 (16 Mi)
  //  +48Mi:       S2T (16 Mi)
  //  +64Mi:       pstat(1Mi) -> QT(8Mi) -> S2TCT(8Mi)  (QT dead after k_mfma_A)
  char* base = (char*)d_ws;
  float*  cw1   = (float*)base;
  float*  qw2   = (float*)(base + 65536);
  char*   R     = base + 131072;
  float*  S     = (float*)R;
  __bf16* Aw    = (__bf16*)R;
  __bf16* CT    = (__bf16*)(R + (16u << 20));
  __bf16* Bmw   = (__bf16*)(R + (16u << 20));
  __bf16* S1    = (__bf16*)(base + 131072 + (32u << 20));
  __bf16* S2T   = (__bf16*)(base + 131072 + (48u << 20));
  char*   Z     = base + 131072 + (64u << 20);
  float2* pstat = (float2*)Z;
  __bf16* QT    = (__bf16*)Z;
  __bf16* S2TCT = (__bf16*)Z;
  (void)in_sizes; (void)n_in; (void)out_size; (void)ws_size;

  k_rowdots<<<(NB * LC + NB * LQ) / 4, 256, 0, stream>>>(C, Q, w, cw1, qw2);
  k_mfma_S<<<dim3(LQ / 128, LC / 128, NB), 512, 0, stream>>>(C, Q, w, cw1, qw2, S);
  k_softstat<<<dim3(LC / 64, NB), 1024, 0, stream>>>(S, qmask, cmask, S1, pstat);
  k_colwrite<<<dim3(LQ / 64, LC / 64, NB), 256, 0, stream>>>(S, cmask, pstat, S2T);
  k_transpose<<<dim3(DM / 64, LQ / 64, NB), 256, 0, stream>>>(Q, QT, LQ, DM);
  k_transpose<<<dim3(DM / 64, LC / 64, NB), 256, 0, stream>>>(C, CT, LC, DM);
  k_mfma_A<<<dim3(DM / 128, LC / 128, NB), 512, 0, stream>>>(S1, QT, Aw);
  k_mfma_T<<<dim3(DM / 128, LQ / 128, NB), 512, 0, stream>>>(S2T, CT, S2TCT);
  k_mfma_Bm<<<dim3(DM / 128, LC / 128, NB), 512, 0, stream>>>(S1, S2TCT, Bmw);
  k_mfma_out<<<dim3(DM / 128, LC / 128, NB), 512, 0, stream>>>(C, Aw, Bmw, out_w, out_b, out);
}

// Round 8
// 281.070 us; speedup vs baseline: 5.8694x; 1.0640x over previous
//
#include <hip/hip_runtime.h>
#include <hip/hip_bf16.h>

// CQAttention: B=16, Lc=1024, Lq=512, d=512.  f32 I/O, bf16 MFMA GEMMs, f32 acc.
// Round 8: register-prefetch software pipeline in all five MFMA GEMMs (next
// chunk's global loads issued between barrier-1 and the MFMA phase, so the
// vmcnt wait lands one iteration later); BK=64 for simple GEMMs (half the
// barriers, 32 MFMA/barrier); k_mfma_out single-pass 4-segment (80 KB LDS,
// 32 MFMA/barrier) with OW pre-converted to bf16 (k_owcvt into dead S2T region).

#define NB 16
#define LC 1024
#define LQ 512
#define DM 512
#define D4 2048
#define NEGINF (-1e30f)
#define LDA64 72   // padded LDS k-stride for BK=64 tiles
#define LDA32 40   // padded LDS k-stride for BK=32 tiles

typedef __bf16 v8bf __attribute__((ext_vector_type(8)));
typedef __bf16 v4bf __attribute__((ext_vector_type(4)));
typedef float  v4f  __attribute__((ext_vector_type(4)));

#define MFMA16 __builtin_amdgcn_mfma_f32_16x16x32_bf16

// 8-wave tile setup: wave (wm 0..1, wn 0..3) owns a 64(m) x 32(n) region.
#define TILE_SETUP8 \
  const int t = threadIdx.x, lane = t & 63, wave = t >> 6; \
  const int wm = wave >> 2, wn = wave & 3, quad = lane >> 4, col = lane & 15; \
  const int sr = t >> 2;

#define ZERO_ACC8 \
  v4f acc[4][2]; \
  _Pragma("unroll") for (int x = 0; x < 4; ++x) \
  _Pragma("unroll") for (int y = 0; y < 2; ++y) \
  _Pragma("unroll") for (int r = 0; r < 4; ++r) acc[x][y][r] = 0.f;

#define FRAG_MMA8S(AL, BL, LDA, KO) do { \
  v8bf af_[4], bf_[2]; \
  _Pragma("unroll") for (int x = 0; x < 4; ++x) \
    af_[x] = *(const v8bf*)&AL[(wm * 64 + x * 16 + col) * LDA + KO + quad * 8]; \
  _Pragma("unroll") for (int y = 0; y < 2; ++y) \
    bf_[y] = *(const v8bf*)&BL[(wn * 32 + y * 16 + col) * LDA + KO + quad * 8]; \
  _Pragma("unroll") for (int x = 0; x < 4; ++x) \
  _Pragma("unroll") for (int y = 0; y < 2; ++y) \
    acc[x][y] = MFMA16(af_[x], bf_[y], acc[x][y], 0, 0, 0); \
} while (0)

// XCD-aware remap (L2 locality for n-tile siblings sharing an A-tile).
__device__ __forceinline__ void xcd_remap(int& bx, int& by, int& bz) {
  const int gx = gridDim.x, gy = gridDim.y, gz = gridDim.z;
  int flat = bx + gx * (by + gy * bz);
  int per = (gx * gy * gz) >> 3;
  int nw = (flat & 7) * per + (flat >> 3);
  bx = nw % gx;
  int r = nw / gx;
  by = r % gy;
  bz = r / gy;
}

__device__ __forceinline__ v8bf cvt8f(float4 a, float4 b) {
  v8bf h;
  h[0] = (__bf16)a.x; h[1] = (__bf16)a.y; h[2] = (__bf16)a.z; h[3] = (__bf16)a.w;
  h[4] = (__bf16)b.x; h[5] = (__bf16)b.y; h[6] = (__bf16)b.z; h[7] = (__bf16)b.w;
  return h;
}

// ---------------- K1: cw1[b,i] = C.w1, qw2[b,j] = Q.w2 ----------------
__global__ void k_rowdots(const float* __restrict__ C, const float* __restrict__ Q,
                          const float* __restrict__ w,
                          float* __restrict__ cw1, float* __restrict__ qw2) {
  const int wid = threadIdx.x >> 6, lane = threadIdx.x & 63;
  const int row = blockIdx.x * 4 + wid;
  const bool isC = row < NB * LC;
  const float* src = isC ? (C + (size_t)row * DM) : (Q + (size_t)(row - NB * LC) * DM);
  const float* wv  = isC ? w : (w + DM);
  float v = 0.f;
#pragma unroll
  for (int tt = 0; tt < 8; ++tt) {
    int k = lane + 64 * tt;
    v += src[k] * wv[k];
  }
#pragma unroll
  for (int off = 32; off; off >>= 1) v += __shfl_down(v, off, 64);
  if (lane == 0) {
    if (isC) cw1[row] = v;
    else     qw2[row - NB * LC] = v;
  }
}

// ------- batched transpose: f32 in[R][Cd] -> bf16 outT[Cd][R] -------
__global__ void k_transpose(const float* __restrict__ in, __bf16* __restrict__ outT,
                            int R, int Cd) {
  __shared__ __bf16 tile[64][66];
  const int b = blockIdx.z;
  const int r0 = blockIdx.y * 64, c0 = blockIdx.x * 64;
  const int tr = threadIdx.x >> 6, tc = threadIdx.x & 63;
  const float* inb = in + (size_t)b * R * Cd;
  __bf16* outb = outT + (size_t)b * Cd * R;
  for (int r = tr; r < 64; r += 4)
    tile[r][tc] = (__bf16)inb[(size_t)(r0 + r) * Cd + c0 + tc];
  __syncthreads();
  for (int c = tr; c < 64; c += 4)
    outb[(size_t)(c0 + c) * R + r0 + tc] = tile[tc][c];
}

// ------- OW f32 -> bf16 (once; reused by all k_mfma_out blocks) -------
__global__ void k_owcvt(const float* __restrict__ OW, __bf16* __restrict__ OWb) {
  size_t i = ((size_t)blockIdx.x * 256 + threadIdx.x) * 4;
  float4 f = *(const float4*)(OW + i);
  v4bf h; h[0] = (__bf16)f.x; h[1] = (__bf16)f.y; h[2] = (__bf16)f.z; h[3] = (__bf16)f.w;
  *(v4bf*)(OWb + i) = h;
}

// ---------------- G1: S = cw1 + qw2 + (C*w3) @ Q^T  (BK=64, prefetch) --------
__global__ __launch_bounds__(512) void k_mfma_S(
    const float* __restrict__ C, const float* __restrict__ Q, const float* __restrict__ w,
    const float* __restrict__ cw1, const float* __restrict__ qw2, float* __restrict__ S) {
  __shared__ __bf16 Al[128 * LDA64], Bl[128 * LDA64];
  int bx = blockIdx.x, by = blockIdx.y, bz = blockIdx.z;
  xcd_remap(bx, by, bz);
  const int b = bz, i0 = by * 128, j0 = bx * 128;
  TILE_SETUP8
  const int skc = (t & 3) * 16;
  const float* Cb = C + (size_t)b * LC * DM;
  const float* Qb = Q + (size_t)b * LQ * DM;
  const float* w3 = w + 2 * DM;
  float4 pc[4], pq[4];
  auto load = [&](int k0) {
    const float* ca = Cb + (size_t)(i0 + sr) * DM + k0 + skc;
    const float* qa = Qb + (size_t)(j0 + sr) * DM + k0 + skc;
#pragma unroll
    for (int u = 0; u < 4; ++u) {
      pc[u] = *(const float4*)(ca + 4 * u);
      pq[u] = *(const float4*)(qa + 4 * u);
    }
  };
  load(0);
  ZERO_ACC8
  for (int k0 = 0; k0 < DM; k0 += 64) {
    const float* wa = w3 + k0 + skc;
#pragma unroll
    for (int u = 0; u < 2; ++u) {
      float4 c0 = pc[2 * u], c1 = pc[2 * u + 1];
      float4 w0 = *(const float4*)(wa + 8 * u), w1 = *(const float4*)(wa + 8 * u + 4);
      v8bf ah;
      ah[0] = (__bf16)(c0.x * w0.x); ah[1] = (__bf16)(c0.y * w0.y);
      ah[2] = (__bf16)(c0.z * w0.z); ah[3] = (__bf16)(c0.w * w0.w);
      ah[4] = (__bf16)(c1.x * w1.x); ah[5] = (__bf16)(c1.y * w1.y);
      ah[6] = (__bf16)(c1.z * w1.z); ah[7] = (__bf16)(c1.w * w1.w);
      *(v8bf*)&Al[sr * LDA64 + skc + 8 * u] = ah;
      *(v8bf*)&Bl[sr * LDA64 + skc + 8 * u] = cvt8f(pq[2 * u], pq[2 * u + 1]);
    }
    __syncthreads();
    int kn = k0 + 64; if (kn >= DM) kn = 0;
    load(kn);                                 // prefetch next chunk
    FRAG_MMA8S(Al, Bl, LDA64, 0);
    FRAG_MMA8S(Al, Bl, LDA64, 32);
    __syncthreads();
  }
  float* Sb = S + (size_t)b * LC * LQ;
#pragma unroll
  for (int x = 0; x < 4; ++x) {
    const int mB = i0 + wm * 64 + x * 16 + quad * 4;
    float cv[4];
#pragma unroll
    for (int r = 0; r < 4; ++r) cv[r] = cw1[b * LC + mB + r];
#pragma unroll
    for (int y = 0; y < 2; ++y) {
      const int j = j0 + wn * 32 + y * 16 + col;
      const float qv = qw2[b * LQ + j];
#pragma unroll
      for (int r = 0; r < 4; ++r)
        Sb[(size_t)(mB + r) * LQ + j] = acc[x][y][r] + cv[r] + qv;
    }
  }
}

// ---- fused: row softmax (qmask) -> S1  AND  per-64i-chunk column stats ----
__global__ __launch_bounds__(1024) void k_softstat(
    const float* __restrict__ S, const float* __restrict__ qmask,
    const float* __restrict__ cmask, __bf16* __restrict__ S1,
    float2* __restrict__ pstat) {
  __shared__ float2 cst[16][LQ];
  const int b = blockIdx.y, ic = blockIdx.x;
  const int tid = threadIdx.x, wv = tid >> 6, lane = tid & 63;
  const float* qm  = qmask + b * LQ;
  const float* cm  = cmask + b * LC + ic * 64;
  const float* Sb  = S  + ((size_t)b * LC + ic * 64) * LQ;
  __bf16*      S1b = S1 + ((size_t)b * LC + ic * 64) * LQ;
  float colm[8], cols[8];
#pragma unroll
  for (int tt = 0; tt < 8; ++tt) { colm[tt] = -3e38f; cols[tt] = 0.f; }
  for (int it = 0; it < 4; ++it) {
    const int r = wv * 4 + it;
    const float cmv = cm[r];
    const float* Srow = Sb + (size_t)r * LQ;
    float sv[8], l1[8];
    float m = -3e38f;
#pragma unroll
    for (int tt = 0; tt < 8; ++tt) {
      int j = lane + 64 * tt;
      sv[tt] = Srow[j];
      float qv = qm[j];
      l1[tt] = qv * sv[tt] + (1.f - qv) * NEGINF;
      m = fmaxf(m, l1[tt]);
    }
#pragma unroll
    for (int off = 32; off; off >>= 1) m = fmaxf(m, __shfl_xor(m, off, 64));
    float e[8], s = 0.f;
#pragma unroll
    for (int tt = 0; tt < 8; ++tt) { e[tt] = __expf(l1[tt] - m); s += e[tt]; }
#pragma unroll
    for (int off = 32; off; off >>= 1) s += __shfl_xor(s, off, 64);
    const float inv = 1.f / s;
#pragma unroll
    for (int tt = 0; tt < 8; ++tt)
      S1b[(size_t)r * LQ + lane + 64 * tt] = (__bf16)(e[tt] * inv);
#pragma unroll
    for (int tt = 0; tt < 8; ++tt) {
      float l2 = cmv * sv[tt] + (1.f - cmv) * NEGINF;
      if (l2 > colm[tt]) { cols[tt] *= __expf(colm[tt] - l2); colm[tt] = l2; }
      cols[tt] += __expf(l2 - colm[tt]);
    }
  }
#pragma unroll
  for (int tt = 0; tt < 8; ++tt) cst[wv][lane + 64 * tt] = make_float2(colm[tt], cols[tt]);
  __syncthreads();
  if (tid < LQ) {
    float M = -3e38f, Sd = 0.f;
#pragma unroll
    for (int k = 0; k < 16; ++k) {
      float2 p = cst[k][tid];
      float nM = fmaxf(M, p.x);
      Sd = Sd * __expf(M - nM) + p.y * __expf(p.x - nM);
      M = nM;
    }
    pstat[((size_t)(b * 16 + ic) * LQ) + tid] = make_float2(M, Sd);
  }
}

// ---- col softmax phase 2: combine chunk stats, write TRANSPOSED S2T[j][i] ----
__global__ void k_colwrite(const float* __restrict__ S, const float* __restrict__ cmask,
                           const float2* __restrict__ pstat, __bf16* __restrict__ S2T) {
  __shared__ float Mf[64], If[64];
  __shared__ __bf16 tile[64][66];
  const int b = blockIdx.z, ic = blockIdx.y, j0 = blockIdx.x * 64;
  const int c = threadIdx.x & 63, ip = threadIdx.x >> 6;
  if (threadIdx.x < 64) {
    float M = -3e38f, Sd = 0.f;
#pragma unroll
    for (int k = 0; k < 16; ++k) {
      float2 p = pstat[((size_t)(b * 16 + k) * LQ) + j0 + threadIdx.x];
      float nM = fmaxf(M, p.x);
      Sd = Sd * __expf(M - nM) + p.y * __expf(p.x - nM);
      M = nM;
    }
    Mf[threadIdx.x] = M; If[threadIdx.x] = 1.f / Sd;
  }
  __syncthreads();
  const float M = Mf[c], inv = If[c];
  const float* Sb = S + ((size_t)b * LC + ic * 64) * LQ;
  const float* cm = cmask + b * LC + ic * 64;
  for (int r = ip; r < 64; r += 4) {
    float mk = cm[r];
    float logit = mk * Sb[(size_t)r * LQ + j0 + c] + (1.f - mk) * NEGINF;
    tile[r][c] = (__bf16)(__expf(logit - M) * inv);
  }
  __syncthreads();
  __bf16* S2Tb = S2T + ((size_t)b * LQ + j0) * LC + ic * 64;
  for (int jr = ip; jr < 64; jr += 4)
    S2Tb[(size_t)jr * LC + c] = tile[c][jr];
}

// ---------------- G2: A = S1 @ Q  (BK=64, prefetch) ----------------
__global__ __launch_bounds__(512) void k_mfma_A(
    const __bf16* __restrict__ S1, const __bf16* __restrict__ QT, __bf16* __restrict__ Aw) {
  __shared__ __bf16 Al[128 * LDA64], Bl[128 * LDA64];
  int bx = blockIdx.x, by = blockIdx.y, bz = blockIdx.z;
  xcd_remap(bx, by, bz);
  const int b = bz, i0 = by * 128, n0 = bx * 128;
  TILE_SETUP8
  const int skc = (t & 3) * 16;
  const __bf16* Ar = S1 + (size_t)b * LC * LQ + (size_t)(i0 + sr) * LQ + skc;
  const __bf16* Br = QT + (size_t)b * DM * LQ + (size_t)(n0 + sr) * LQ + skc;
  v8bf pa0, pa1, pb0, pb1;
  auto load = [&](int k0) {
    pa0 = *(const v8bf*)(Ar + k0); pa1 = *(const v8bf*)(Ar + k0 + 8);
    pb0 = *(const v8bf*)(Br + k0); pb1 = *(const v8bf*)(Br + k0 + 8);
  };
  load(0);
  ZERO_ACC8
  for (int k0 = 0; k0 < LQ; k0 += 64) {
    *(v8bf*)&Al[sr * LDA64 + skc] = pa0; *(v8bf*)&Al[sr * LDA64 + skc + 8] = pa1;
    *(v8bf*)&Bl[sr * LDA64 + skc] = pb0; *(v8bf*)&Bl[sr * LDA64 + skc + 8] = pb1;
    __syncthreads();
    int kn = k0 + 64; if (kn >= LQ) kn = 0;
    load(kn);
    FRAG_MMA8S(Al, Bl, LDA64, 0);
    FRAG_MMA8S(Al, Bl, LDA64, 32);
    __syncthreads();
  }
  __bf16* Ab = Aw + (size_t)b * LC * DM;
#pragma unroll
  for (int x = 0; x < 4; ++x) {
    const int mB = i0 + wm * 64 + x * 16 + quad * 4;
#pragma unroll
    for (int y = 0; y < 2; ++y) {
      const int n = n0 + wn * 32 + y * 16 + col;
#pragma unroll
      for (int r = 0; r < 4; ++r)
        Ab[(size_t)(mB + r) * DM + n] = (__bf16)acc[x][y][r];
    }
  }
}

// ------- G3: S2TC^T[n][j]  (A=S2T rows, B=CT rows; K=Lc, BK=64, prefetch) ----
__global__ __launch_bounds__(512) void k_mfma_T(
    const __bf16* __restrict__ S2T, const __bf16* __restrict__ CT, __bf16* __restrict__ S2TCT) {
  __shared__ __bf16 Al[128 * LDA64], Bl[128 * LDA64];
  int bx = blockIdx.x, by = blockIdx.y, bz = blockIdx.z;
  xcd_remap(bx, by, bz);
  const int b = bz, j0 = by * 128, n0 = bx * 128;
  TILE_SETUP8
  const int skc = (t & 3) * 16;
  const __bf16* Ar = S2T + (size_t)b * LQ * LC + (size_t)(j0 + sr) * LC + skc;
  const __bf16* Br = CT  + (size_t)b * DM * LC + (size_t)(n0 + sr) * LC + skc;
  v8bf pa0, pa1, pb0, pb1;
  auto load = [&](int k0) {
    pa0 = *(const v8bf*)(Ar + k0); pa1 = *(const v8bf*)(Ar + k0 + 8);
    pb0 = *(const v8bf*)(Br + k0); pb1 = *(const v8bf*)(Br + k0 + 8);
  };
  load(0);
  ZERO_ACC8
  for (int k0 = 0; k0 < LC; k0 += 64) {
    *(v8bf*)&Al[sr * LDA64 + skc] = pa0; *(v8bf*)&Al[sr * LDA64 + skc + 8] = pa1;
    *(v8bf*)&Bl[sr * LDA64 + skc] = pb0; *(v8bf*)&Bl[sr * LDA64 + skc + 8] = pb1;
    __syncthreads();
    int kn = k0 + 64; if (kn >= LC) kn = 0;
    load(kn);
    FRAG_MMA8S(Al, Bl, LDA64, 0);
    FRAG_MMA8S(Al, Bl, LDA64, 32);
    __syncthreads();
  }
#pragma unroll
  for (int x = 0; x < 4; ++x) {
    const int jB = j0 + wm * 64 + x * 16 + quad * 4;
#pragma unroll
    for (int y = 0; y < 2; ++y) {
      const int n = n0 + wn * 32 + y * 16 + col;
      v4bf h;
#pragma unroll
      for (int r = 0; r < 4; ++r) h[r] = (__bf16)acc[x][y][r];
      *(v4bf*)&S2TCT[((size_t)b * DM + n) * LQ + jB] = h;
    }
  }
}

// ---------------- G4: Bm = S1 @ S2TC  (BK=64, prefetch) ----------------
__global__ __launch_bounds__(512) void k_mfma_Bm(
    const __bf16* __restrict__ S1, const __bf16* __restrict__ S2TCT, __bf16* __restrict__ Bmw) {
  __shared__ __bf16 Al[128 * LDA64], Bl[128 * LDA64];
  int bx = blockIdx.x, by = blockIdx.y, bz = blockIdx.z;
  xcd_remap(bx, by, bz);
  const int b = bz, i0 = by * 128, n0 = bx * 128;
  TILE_SETUP8
  const int skc = (t & 3) * 16;
  const __bf16* Ar = S1    + (size_t)b * LC * LQ + (size_t)(i0 + sr) * LQ + skc;
  const __bf16* Br = S2TCT + (size_t)b * DM * LQ + (size_t)(n0 + sr) * LQ + skc;
  v8bf pa0, pa1, pb0, pb1;
  auto load = [&](int k0) {
    pa0 = *(const v8bf*)(Ar + k0); pa1 = *(const v8bf*)(Ar + k0 + 8);
    pb0 = *(const v8bf*)(Br + k0); pb1 = *(const v8bf*)(Br + k0 + 8);
  };
  load(0);
  ZERO_ACC8
  for (int k0 = 0; k0 < LQ; k0 += 64) {
    *(v8bf*)&Al[sr * LDA64 + skc] = pa0; *(v8bf*)&Al[sr * LDA64 + skc + 8] = pa1;
    *(v8bf*)&Bl[sr * LDA64 + skc] = pb0; *(v8bf*)&Bl[sr * LDA64 + skc + 8] = pb1;
    __syncthreads();
    int kn = k0 + 64; if (kn >= LQ) kn = 0;
    load(kn);
    FRAG_MMA8S(Al, Bl, LDA64, 0);
    FRAG_MMA8S(Al, Bl, LDA64, 32);
    __syncthreads();
  }
  __bf16* Bb = Bmw + (size_t)b * LC * DM;
#pragma unroll
  for (int x = 0; x < 4; ++x) {
    const int mB = i0 + wm * 64 + x * 16 + quad * 4;
#pragma unroll
    for (int y = 0; y < 2; ++y) {
      const int n = n0 + wn * 32 + y * 16 + col;
#pragma unroll
      for (int r = 0; r < 4; ++r)
        Bb[(size_t)(mB + r) * DM + n] = (__bf16)acc[x][y][r];
    }
  }
}

// -------- G5: out = [C, A, C*A, C*Bm] @ out_w^T + out_b  (1-pass 4-seg) ------
__global__ __launch_bounds__(512) void k_mfma_out(
    const float* __restrict__ C, const __bf16* __restrict__ Aw, const __bf16* __restrict__ Bmw,
    const __bf16* __restrict__ OWb, const float* __restrict__ ob, float* __restrict__ out) {
  __shared__ __bf16 Asg[4][128 * LDA32], Bsg[4][128 * LDA32];   // 80 KiB
  int bx = blockIdx.x, by = blockIdx.y, bz = blockIdx.z;
  xcd_remap(bx, by, bz);
  const int b = bz, i0 = by * 128, n0 = bx * 128;
  TILE_SETUP8
  const int skc = (t & 3) * 8;
  const float*  Cr = C   + (size_t)b * LC * DM + (size_t)(i0 + sr) * DM + skc;
  const __bf16* Ar = Aw  + (size_t)b * LC * DM + (size_t)(i0 + sr) * DM + skc;
  const __bf16* Br = Bmw + (size_t)b * LC * DM + (size_t)(i0 + sr) * DM + skc;
  const __bf16* Wr = OWb + (size_t)(n0 + sr) * D4 + skc;
  float4 pc0, pc1; v8bf pA, pB, pw[4];
  auto load = [&](int kl) {
    pc0 = *(const float4*)(Cr + kl); pc1 = *(const float4*)(Cr + kl + 4);
    pA = *(const v8bf*)(Ar + kl);
    pB = *(const v8bf*)(Br + kl);
#pragma unroll
    for (int s = 0; s < 4; ++s) pw[s] = *(const v8bf*)(Wr + s * DM + kl);
  };
  load(0);
  ZERO_ACC8
  for (int kl = 0; kl < DM; kl += 32) {
    float cf[8] = {pc0.x, pc0.y, pc0.z, pc0.w, pc1.x, pc1.y, pc1.z, pc1.w};
    v8bf hC, hCA, hCB;
#pragma unroll
    for (int e = 0; e < 8; ++e) {
      hC[e]  = (__bf16)cf[e];
      hCA[e] = (__bf16)(cf[e] * (float)pA[e]);
      hCB[e] = (__bf16)(cf[e] * (float)pB[e]);
    }
    const int off = sr * LDA32 + skc;
    *(v8bf*)&Asg[0][off] = hC;
    *(v8bf*)&Asg[1][off] = pA;
    *(v8bf*)&Asg[2][off] = hCA;
    *(v8bf*)&Asg[3][off] = hCB;
#pragma unroll
    for (int s = 0; s < 4; ++s) *(v8bf*)&Bsg[s][off] = pw[s];
    __syncthreads();
    int kn = kl + 32; if (kn >= DM) kn = 0;
    load(kn);                                 // prefetch next chunk
#pragma unroll
    for (int s = 0; s < 4; ++s) FRAG_MMA8S(Asg[s], Bsg[s], LDA32, 0);
    __syncthreads();
  }
  float* outb = out + (size_t)b * LC * DM;
#pragma unroll
  for (int x = 0; x < 4; ++x) {
    const int mB = i0 + wm * 64 + x * 16 + quad * 4;
#pragma unroll
    for (int y = 0; y < 2; ++y) {
      const int n = n0 + wn * 32 + y * 16 + col;
      const float bv = ob[n];
#pragma unroll
      for (int r = 0; r < 4; ++r)
        outb[(size_t)(mB + r) * DM + n] = acc[x][y][r] + bv;
    }
  }
}

extern "C" void kernel_launch(void* const* d_in, const int* in_sizes, int n_in,
                              void* d_out, int out_size, void* d_ws, size_t ws_size,
                              hipStream_t stream) {
  const float* C     = (const float*)d_in[0];
  const float* Q     = (const float*)d_in[1];
  const float* cmask = (const float*)d_in[2];
  const float* qmask = (const float*)d_in[3];
  const float* w     = (const float*)d_in[4];
  const float* out_w = (const float*)d_in[5];
  const float* out_b = (const float*)d_in[6];
  float* out = (float*)d_out;

  // ---- workspace carve (72 MiB + 128 KiB; validated). Aliased by lifetime:
  //  R[0,16Mi):   S.lo          -> Aw
  //  R[16,32Mi):  S.hi          -> CT -> Bmw
  //  +32Mi: S1 (16 Mi)
  //  +48Mi: S2T (16 Mi)        -> OWbf (2 Mi, after k_mfma_T)
  //  +64Mi: pstat(1Mi) -> QT(8Mi) -> S2TCT(8Mi)
  char* base = (char*)d_ws;
  float*  cw1   = (float*)base;
  float*  qw2   = (float*)(base + 65536);
  char*   R     = base + 131072;
  float*  S     = (float*)R;
  __bf16* Aw    = (__bf16*)R;
  __bf16* CT    = (__bf16*)(R + (16u << 20));
  __bf16* Bmw   = (__bf16*)(R + (16u << 20));
  __bf16* S1    = (__bf16*)(base + 131072 + (32u << 20));
  __bf16* S2T   = (__bf16*)(base + 131072 + (48u << 20));
  __bf16* OWbf  = S2T;   // 2 MiB, written after k_mfma_T consumes S2T
  char*   Z     = base + 131072 + (64u << 20);
  float2* pstat = (float2*)Z;
  __bf16* QT    = (__bf16*)Z;
  __bf16* S2TCT = (__bf16*)Z;
  (void)in_sizes; (void)n_in; (void)out_size; (void)ws_size;

  k_rowdots<<<(NB * LC + NB * LQ) / 4, 256, 0, stream>>>(C, Q, w, cw1, qw2);
  k_mfma_S<<<dim3(LQ / 128, LC / 128, NB), 512, 0, stream>>>(C, Q, w, cw1, qw2, S);
  k_softstat<<<dim3(LC / 64, NB), 1024, 0, stream>>>(S, qmask, cmask, S1, pstat);
  k_colwrite<<<dim3(LQ / 64, LC / 64, NB), 256, 0, stream>>>(S, cmask, pstat, S2T);
  k_transpose<<<dim3(DM / 64, LQ / 64, NB), 256, 0, stream>>>(Q, QT, LQ, DM);
  k_transpose<<<dim3(DM / 64, LC / 64, NB), 256, 0, stream>>>(C, CT, LC, DM);
  k_mfma_A<<<dim3(DM / 128, LC / 128, NB), 512, 0, stream>>>(S1, QT, Aw);
  k_mfma_T<<<dim3(DM / 128, LQ / 128, NB), 512, 0, stream>>>(S2T, CT, S2TCT);
  k_owcvt<<<DM * D4 / 1024, 256, 0, stream>>>(out_w, OWbf);
  k_mfma_Bm<<<dim3(DM / 128, LC / 128, NB), 512, 0, stream>>>(S1, S2TCT, Bmw);
  k_mfma_out<<<dim3(DM / 128, LC / 128, NB), 512, 0, stream>>>(C, Aw, Bmw, OWbf, out_b, out);
}